// Round 4
// baseline (640.072 us; speedup 1.0000x reference)
//
#include <hip/hip_runtime.h>
#include <hip/hip_bf16.h>
#include <stdint.h>

#define NN 100000
#define EE 1600000
#define NBUCK 782              // ceil(NN/128)

typedef __attribute__((ext_vector_type(4))) float f32x4;
typedef __attribute__((ext_vector_type(8))) short bf16x8;

__device__ inline ushort f2bf(float f) {
    union { float f; uint32_t u; } v; v.f = f;
    uint32_t u = v.u;
    uint32_t r = (u + 0x7fffu + ((u >> 16) & 1u)) >> 16;   // RNE
    return (ushort)r;
}
__device__ inline float bf2f(ushort h) {
    union { uint32_t u; float f; } v; v.u = ((uint32_t)h) << 16; return v.f;
}
__device__ inline float bflo(uint32_t u) {
    union { uint32_t u; float f; } v; v.u = u << 16; return v.f;
}
__device__ inline float bfhi(uint32_t u) {
    union { uint32_t u; float f; } v; v.u = u & 0xffff0000u; return v.f;
}

// ---------------- edge dtype detect ----------------
__global__ void detect_kernel(const unsigned int* raw, int* flag) {
    int i = blockIdx.x * blockDim.x + threadIdx.x;
    if (i < 4096) {
        if (raw[2 * i + 1] != 0u) atomicOr(flag, 1);
    }
}

// ---------------- dtype conversion passes ----------------
__global__ void cvt_f32_bf16(const float* __restrict__ in, ushort* __restrict__ out, int n4) {
    int i = blockIdx.x * blockDim.x + threadIdx.x;   // one float4 per thread
    if (i >= n4) return;
    float4 v = *(const float4*)&in[i * 4];
    ushort o[4] = { f2bf(v.x), f2bf(v.y), f2bf(v.z), f2bf(v.w) };
    *(uint64_t*)&out[i * 4] = *(const uint64_t*)o;
}

// Wcat[o][0..K) = Wl[o][:], Wcat[o][K..2K) = Wr[o][:]  (bf16)
__global__ void build_wcat(const float* __restrict__ Wl, const float* __restrict__ Wr,
                           ushort* __restrict__ Wcat, int K) {
    int t = blockIdx.x * blockDim.x + threadIdx.x;
    int KT = 2 * K;
    if (t >= 128 * KT) return;
    int o = t / KT, k = t % KT;
    float v = (k < K) ? Wl[o * K + k] : Wr[o * K + (k - K)];
    Wcat[o * KT + k] = f2bf(v);
}

// ---------------- CSR build: two-level partition ----------------
// Pass A: coarse histogram (LDS-staged, 512 grid-stride blocks)
__global__ __launch_bounds__(256) void coarse_hist(const void* raw, const int* flag,
                                                   int* ccnt, int E) {
    __shared__ int lh[NBUCK];
    for (int i = threadIdx.x; i < NBUCK; i += 256) lh[i] = 0;
    __syncthreads();
    int stride = gridDim.x * 256;
    if (*flag) {
        const int* p = (const int*)raw;
        for (int e = blockIdx.x * 256 + threadIdx.x; e < E; e += stride)
            atomicAdd(&lh[p[E + e] >> 7], 1);
    } else {
        const long long* p = (const long long*)raw;
        for (int e = blockIdx.x * 256 + threadIdx.x; e < E; e += stride)
            atomicAdd(&lh[(int)p[E + e] >> 7], 1);
    }
    __syncthreads();
    for (int i = threadIdx.x; i < NBUCK; i += 256)
        if (lh[i]) atomicAdd(&ccnt[i], lh[i]);
}

// Pass B: exclusive scan of 782 bucket counts (single block)
__global__ void coarse_scan(const int* ccnt, int* coff, int* offsets, int E) {
    __shared__ int part[256];
    int t = threadIdx.x;
    int v[4]; int s = 0;
    #pragma unroll
    for (int j = 0; j < 4; j++) {
        int i = t * 4 + j;
        v[j] = (i < NBUCK) ? ccnt[i] : 0;
        s += v[j];
    }
    part[t] = s; __syncthreads();
    for (int off = 1; off < 256; off <<= 1) {
        int add = (t >= off) ? part[t - off] : 0;
        __syncthreads();
        part[t] += add;
        __syncthreads();
    }
    int run = part[t] - s;
    #pragma unroll
    for (int j = 0; j < 4; j++) {
        int i = t * 4 + j;
        if (i <= NBUCK) coff[i] = run;
        run += v[j];
    }
    if (t == 0) offsets[NN] = E;
}

// Pass C: scatter packed edges into coarse buckets (dense frontiers -> no WB blowup)
__global__ __launch_bounds__(256) void coarse_scatter(const void* raw, const int* flag,
                                                      const int* coff, int* cfill,
                                                      uint32_t* pbuf, int E) {
    int e = blockIdx.x * 256 + threadIdx.x;
    if (e >= E) return;
    int s, d;
    if (*flag) {
        const int* p = (const int*)raw;
        s = p[e]; d = p[E + e];
    } else {
        const long long* p = (const long long*)raw;
        s = (int)p[e]; d = (int)p[E + e];
    }
    int b = d >> 7;
    int pos = coff[b] + atomicAdd(&cfill[b], 1);
    pbuf[pos] = ((uint32_t)(d & 127) << 17) | (uint32_t)s;   // src < 2^17
}

// Pass D: within each coarse bucket, build per-node offsets + final sorted srcs.
// All writes land in the bucket's contiguous range (~8KB) -> L2-resident.
__global__ __launch_bounds__(256) void fine_bucket(const uint32_t* __restrict__ pbuf,
                                                   const int* __restrict__ coff,
                                                   int* __restrict__ offsets,
                                                   int* __restrict__ srcs_sort, int N) {
    __shared__ int cnt[128], sc[128], fil[128];
    int b = blockIdx.x, t = threadIdx.x;
    int s = coff[b], e = coff[b + 1];
    if (t < 128) { cnt[t] = 0; fil[t] = 0; }
    __syncthreads();
    for (int i = s + t; i < e; i += 256) atomicAdd(&cnt[pbuf[i] >> 17], 1);
    __syncthreads();
    if (t < 128) sc[t] = cnt[t];
    __syncthreads();
    for (int off = 1; off < 128; off <<= 1) {
        int add = (t < 128 && t >= off) ? sc[t - off] : 0;
        __syncthreads();
        if (t < 128) sc[t] += add;
        __syncthreads();
    }
    int nb0 = b * 128;
    if (t < 128 && nb0 + t < N) offsets[nb0 + t] = s + sc[t] - cnt[t];
    for (int i = s + t; i < e; i += 256) {
        uint32_t p = pbuf[i];
        int dl = p >> 17;
        int sr = (int)(p & 0x1FFFFu);
        int pos = s + (sc[dl] - cnt[dl]) + atomicAdd(&fil[dl], 1);
        srcs_sort[pos] = sr;
    }
}

// ---------------- mean aggregation (bf16 in, bf16 out): one wave per node ----------------
template<int K>
__global__ void aggregate_kernel(const int* __restrict__ offsets, const int* __restrict__ srcs,
                                 const ushort* __restrict__ xb, ushort* __restrict__ meanb, int N) {
    int wave = threadIdx.x >> 6;
    int lane = threadIdx.x & 63;
    int node = blockIdx.x * 4 + wave;   // blockDim = 256
    if (node >= N) return;
    int s0 = offsets[node], s1 = offsets[node + 1];
    float inv = 1.0f / fmaxf((float)(s1 - s0), 1.0f);

    if (K == 64) {
        float a0 = 0.f, a1 = 0.f, a2 = 0.f, a3 = 0.f;
        for (int base = s0; base < s1; base += 64) {
            int cnt = min(64, s1 - base);
            int myidx = (base + lane < s1) ? srcs[base + lane] : 0;
            int j = 0;
            for (; j + 4 <= cnt; j += 4) {
                int sa = __shfl(myidx, j);
                int sb = __shfl(myidx, j + 1);
                int sc_ = __shfl(myidx, j + 2);
                int sd = __shfl(myidx, j + 3);
                float va = bf2f(xb[(size_t)sa * 64 + lane]);
                float vb = bf2f(xb[(size_t)sb * 64 + lane]);
                float vc = bf2f(xb[(size_t)sc_ * 64 + lane]);
                float vd = bf2f(xb[(size_t)sd * 64 + lane]);
                a0 += va; a1 += vb; a2 += vc; a3 += vd;
            }
            for (; j < cnt; j++) {
                int s = __shfl(myidx, j);
                a0 += bf2f(xb[(size_t)s * 64 + lane]);
            }
        }
        meanb[(size_t)node * 64 + lane] = f2bf((a0 + a1 + a2 + a3) * inv);
    } else {
        float x0 = 0.f, y0 = 0.f, x1 = 0.f, y1 = 0.f;
        float x2 = 0.f, y2 = 0.f, x3 = 0.f, y3 = 0.f;
        for (int base = s0; base < s1; base += 64) {
            int cnt = min(64, s1 - base);
            int myidx = (base + lane < s1) ? srcs[base + lane] : 0;
            int j = 0;
            for (; j + 4 <= cnt; j += 4) {
                int sa = __shfl(myidx, j);
                int sb = __shfl(myidx, j + 1);
                int sc_ = __shfl(myidx, j + 2);
                int sd = __shfl(myidx, j + 3);
                uint32_t ua = *(const uint32_t*)&xb[(size_t)sa * 128 + 2 * lane];
                uint32_t ub = *(const uint32_t*)&xb[(size_t)sb * 128 + 2 * lane];
                uint32_t uc = *(const uint32_t*)&xb[(size_t)sc_ * 128 + 2 * lane];
                uint32_t ud = *(const uint32_t*)&xb[(size_t)sd * 128 + 2 * lane];
                x0 += bflo(ua); y0 += bfhi(ua);
                x1 += bflo(ub); y1 += bfhi(ub);
                x2 += bflo(uc); y2 += bfhi(uc);
                x3 += bflo(ud); y3 += bfhi(ud);
            }
            for (; j < cnt; j++) {
                int s = __shfl(myidx, j);
                uint32_t u = *(const uint32_t*)&xb[(size_t)s * 128 + 2 * lane];
                x0 += bflo(u); y0 += bfhi(u);
            }
        }
        ushort o[2] = { f2bf((x0 + x1 + x2 + x3) * inv), f2bf((y0 + y1 + y2 + y3) * inv) };
        *(uint32_t*)&meanb[(size_t)node * 128 + 2 * lane] = *(const uint32_t*)o;
    }
}

// ---------------- MFMA SAGE linear: out = [mean|self] @ Wcat^T + bl ----------------
template<int K, bool RELU, bool OUT_BF16>
__global__ __launch_bounds__(256) void sage_gemm_mfma(
    const ushort* __restrict__ meanb, const ushort* __restrict__ selfb,
    const ushort* __restrict__ Wcat, const float* __restrict__ bl,
    void* __restrict__ outv, int N)
{
    const int KT = 2 * K;
    const int wave = threadIdx.x >> 6;
    const int lane = threadIdx.x & 63;
    const int lrow = lane & 15;
    const int lgrp = lane >> 4;
    const int n0 = blockIdx.x * 128 + wave * 32;

    f32x4 acc[2][8];
    #pragma unroll
    for (int h = 0; h < 2; h++)
        #pragma unroll
        for (int t = 0; t < 8; t++)
            acc[h][t] = (f32x4){0.f, 0.f, 0.f, 0.f};

    const int ar0 = min(n0 + lrow, N - 1);
    const int ar1 = min(n0 + 16 + lrow, N - 1);

    #pragma unroll
    for (int ks = 0; ks < KT; ks += 32) {
        const ushort* Ap = (ks < K) ? meanb : selfb;
        const int ac = (ks < K) ? ks : (ks - K);
        bf16x8 a0 = *(const bf16x8*)&Ap[(size_t)ar0 * K + ac + lgrp * 8];
        bf16x8 a1 = *(const bf16x8*)&Ap[(size_t)ar1 * K + ac + lgrp * 8];
        #pragma unroll
        for (int t = 0; t < 8; t++) {
            bf16x8 b = *(const bf16x8*)&Wcat[(size_t)(t * 16 + lrow) * KT + ks + lgrp * 8];
            acc[0][t] = __builtin_amdgcn_mfma_f32_16x16x32_bf16(a0, b, acc[0][t], 0, 0, 0);
            acc[1][t] = __builtin_amdgcn_mfma_f32_16x16x32_bf16(a1, b, acc[1][t], 0, 0, 0);
        }
    }

    #pragma unroll
    for (int t = 0; t < 8; t++) {
        int c = t * 16 + lrow;
        float bias = bl[c];
        #pragma unroll
        for (int h = 0; h < 2; h++) {
            #pragma unroll
            for (int r = 0; r < 4; r++) {
                int n = n0 + h * 16 + lgrp * 4 + r;
                if (n < N) {
                    float v = acc[h][t][r] + bias;
                    if (RELU) v = fmaxf(v, 0.0f);
                    if (OUT_BF16) ((ushort*)outv)[(size_t)n * 128 + c] = f2bf(v);
                    else         ((float*)outv)[(size_t)n * 128 + c] = v;
                }
            }
        }
    }
}

// ---------------- launch ----------------
extern "C" void kernel_launch(void* const* d_in, const int* in_sizes, int n_in,
                              void* d_out, int out_size, void* d_ws, size_t ws_size,
                              hipStream_t stream) {
    const float* x   = (const float*)d_in[0];
    const void*  er  = d_in[1];
    const float* Wl1 = (const float*)d_in[2];
    const float* bl1 = (const float*)d_in[3];
    const float* Wr1 = (const float*)d_in[4];
    const float* Wl2 = (const float*)d_in[5];
    const float* bl2 = (const float*)d_in[6];
    const float* Wr2 = (const float*)d_in[7];
    float* out = (float*)d_out;

    const int N = NN, E = EE;

    // workspace carve-up (512B aligned)
    char* ws = (char*)d_ws;
    size_t off = 0;
    auto carve = [&](size_t bytes) { char* p = ws + off; off += (bytes + 511) & ~(size_t)511; return p; };
    int*      flag      = (int*)     carve(4);
    int*      ccnt      = (int*)     carve((size_t)NBUCK * 4);
    int*      cfill     = (int*)     carve((size_t)NBUCK * 4);
    int*      coff      = (int*)     carve((size_t)(NBUCK + 1) * 4);
    uint32_t* pbuf      = (uint32_t*)carve((size_t)E * 4);
    int*      offsets   = (int*)     carve((size_t)(N + 1) * 4);
    int*      srcs_sort = (int*)     carve((size_t)E * 4);
    ushort*   xb        = (ushort*)  carve((size_t)N * 64 * 2);
    ushort*   meanb     = (ushort*)  carve((size_t)N * 128 * 2);
    ushort*   hb        = (ushort*)  carve((size_t)N * 128 * 2);
    ushort*   wc1       = (ushort*)  carve((size_t)128 * 128 * 2);
    ushort*   wc2       = (ushort*)  carve((size_t)128 * 256 * 2);
    (void)ws_size;

    const int eb = (E + 255) / 256;                          // 6250

    hipMemsetAsync(flag, 0, 4, stream);
    hipMemsetAsync(ccnt, 0, (size_t)NBUCK * 4, stream);
    hipMemsetAsync(cfill, 0, (size_t)NBUCK * 4, stream);

    detect_kernel<<<16, 256, 0, stream>>>((const unsigned int*)er, flag);

    // bf16 conversions (independent of CSR build)
    cvt_f32_bf16<<<(N * 64 / 4 + 255) / 256, 256, 0, stream>>>(x, xb, N * 64 / 4);
    build_wcat<<<(128 * 128 + 255) / 256, 256, 0, stream>>>(Wl1, Wr1, wc1, 64);
    build_wcat<<<(128 * 256 + 255) / 256, 256, 0, stream>>>(Wl2, Wr2, wc2, 128);

    // CSR build: two-level partition
    coarse_hist<<<512, 256, 0, stream>>>(er, flag, ccnt, E);
    coarse_scan<<<1, 256, 0, stream>>>(ccnt, coff, offsets, E);
    coarse_scatter<<<eb, 256, 0, stream>>>(er, flag, coff, cfill, pbuf, E);
    fine_bucket<<<NBUCK, 256, 0, stream>>>(pbuf, coff, offsets, srcs_sort, N);

    const int ab = (N + 3) / 4;                              // 25000 (4 waves/block)
    const int gb = (N + 127) / 128;                          // 782

    // layer 1
    aggregate_kernel<64><<<ab, 256, 0, stream>>>(offsets, srcs_sort, xb, meanb, N);
    sage_gemm_mfma<64, true, true><<<gb, 256, 0, stream>>>(meanb, xb, wc1, bl1, hb, N);

    // layer 2
    aggregate_kernel<128><<<ab, 256, 0, stream>>>(offsets, srcs_sort, hb, meanb, N);
    sage_gemm_mfma<128, false, false><<<gb, 256, 0, stream>>>(meanb, hb, wc2, bl2, out, N);
}

// Round 5
// 282.799 us; speedup vs baseline: 2.2633x; 2.2633x over previous
//
#include <hip/hip_runtime.h>
#include <hip/hip_bf16.h>
#include <stdint.h>

#define NN 100000
#define EE 1600000
#define NBUCK 196              // ceil(NN/512): buckets of 512 dst nodes
#define CSB 512                // coarse-scatter blocks

typedef __attribute__((ext_vector_type(4))) float f32x4;
typedef __attribute__((ext_vector_type(8))) short bf16x8;

__device__ inline ushort f2bf(float f) {
    union { float f; uint32_t u; } v; v.f = f;
    uint32_t u = v.u;
    uint32_t r = (u + 0x7fffu + ((u >> 16) & 1u)) >> 16;   // RNE
    return (ushort)r;
}
__device__ inline float bf2f(ushort h) {
    union { uint32_t u; float f; } v; v.u = ((uint32_t)h) << 16; return v.f;
}
__device__ inline float bflo(uint32_t u) {
    union { uint32_t u; float f; } v; v.u = u << 16; return v.f;
}
__device__ inline float bfhi(uint32_t u) {
    union { uint32_t u; float f; } v; v.u = u & 0xffff0000u; return v.f;
}

// ---------------- edge dtype detect ----------------
__global__ void detect_kernel(const unsigned int* raw, int* flag) {
    int i = blockIdx.x * blockDim.x + threadIdx.x;
    if (i < 4096) {
        if (raw[2 * i + 1] != 0u) atomicOr(flag, 1);
    }
}

// ---------------- dtype conversion passes ----------------
__global__ void cvt_f32_bf16(const float* __restrict__ in, ushort* __restrict__ out, int n4) {
    int i = blockIdx.x * blockDim.x + threadIdx.x;   // one float4 per thread
    if (i >= n4) return;
    float4 v = *(const float4*)&in[i * 4];
    ushort o[4] = { f2bf(v.x), f2bf(v.y), f2bf(v.z), f2bf(v.w) };
    *(uint64_t*)&out[i * 4] = *(const uint64_t*)o;
}

// Wcat[o][0..K) = Wl[o][:], Wcat[o][K..2K) = Wr[o][:]  (bf16)
__global__ void build_wcat(const float* __restrict__ Wl, const float* __restrict__ Wr,
                           ushort* __restrict__ Wcat, int K) {
    int t = blockIdx.x * blockDim.x + threadIdx.x;
    int KT = 2 * K;
    if (t >= 128 * KT) return;
    int o = t / KT, k = t % KT;
    float v = (k < K) ? Wl[o * K + k] : Wr[o * K + (k - K)];
    Wcat[o * KT + k] = f2bf(v);
}

// ---------------- CSR build: two-level partition (block-reserved) ----------------
// Pass A: coarse histogram (LDS-staged)
__global__ __launch_bounds__(256) void coarse_hist(const void* raw, const int* flag,
                                                   int* ccnt, int E) {
    __shared__ int lh[NBUCK];
    for (int i = threadIdx.x; i < NBUCK; i += 256) lh[i] = 0;
    __syncthreads();
    int stride = gridDim.x * 256;
    if (*flag) {
        const int* p = (const int*)raw;
        for (int e = blockIdx.x * 256 + threadIdx.x; e < E; e += stride)
            atomicAdd(&lh[p[E + e] >> 9], 1);
    } else {
        const long long* p = (const long long*)raw;
        for (int e = blockIdx.x * 256 + threadIdx.x; e < E; e += stride)
            atomicAdd(&lh[((int)p[E + e]) >> 9], 1);
    }
    __syncthreads();
    for (int i = threadIdx.x; i < NBUCK; i += 256)
        if (lh[i]) atomicAdd(&ccnt[i], lh[i]);
}

// Pass B: exclusive scan of bucket counts (single block)
__global__ void coarse_scan(const int* ccnt, int* coff, int* offsets, int E) {
    __shared__ int part[256];
    int t = threadIdx.x;
    int v[4]; int s = 0;
    #pragma unroll
    for (int j = 0; j < 4; j++) {
        int i = t * 4 + j;
        v[j] = (i < NBUCK) ? ccnt[i] : 0;
        s += v[j];
    }
    part[t] = s; __syncthreads();
    for (int off = 1; off < 256; off <<= 1) {
        int add = (t >= off) ? part[t - off] : 0;
        __syncthreads();
        part[t] += add;
        __syncthreads();
    }
    int run = part[t] - s;
    #pragma unroll
    for (int j = 0; j < 4; j++) {
        int i = t * 4 + j;
        if (i <= NBUCK) coff[i] = run;
        run += v[j];
    }
    if (t == 0) offsets[NN] = E;
}

// Pass C: block-reserved scatter. Each block LDS-histograms its chunk, reserves
// per-bucket space with ONE global atomic per (block,bucket), then writes dense
// runs (~16 entries = full 64B lines). Packed entry: (dst&511)<<17 | src.
__global__ __launch_bounds__(256) void coarse_scatter2(const void* raw, const int* flag,
                                                       const int* coff, int* cfill,
                                                       uint32_t* pbuf, int E) {
    __shared__ int lh[NBUCK];
    __shared__ int gbase[NBUCK];
    __shared__ int lfill[NBUCK];
    const int t = threadIdx.x;
    for (int i = t; i < NBUCK; i += 256) { lh[i] = 0; lfill[i] = 0; }
    __syncthreads();
    const int chunk = (E + (int)gridDim.x - 1) / (int)gridDim.x;
    const int s0 = blockIdx.x * chunk;
    const int s1 = min(E, s0 + chunk);
    const bool is32 = (*flag != 0);
    if (is32) {
        const int* p = (const int*)raw;
        for (int e = s0 + t; e < s1; e += 256) atomicAdd(&lh[p[E + e] >> 9], 1);
    } else {
        const long long* p = (const long long*)raw;
        for (int e = s0 + t; e < s1; e += 256) atomicAdd(&lh[((int)p[E + e]) >> 9], 1);
    }
    __syncthreads();
    for (int i = t; i < NBUCK; i += 256)
        gbase[i] = coff[i] + (lh[i] ? atomicAdd(&cfill[i], lh[i]) : 0);
    __syncthreads();
    if (is32) {
        const int* p = (const int*)raw;
        for (int e = s0 + t; e < s1; e += 256) {
            int sr = p[e], d = p[E + e];
            int b = d >> 9;
            int r = atomicAdd(&lfill[b], 1);
            pbuf[gbase[b] + r] = ((uint32_t)(d & 511) << 17) | (uint32_t)sr;
        }
    } else {
        const long long* p = (const long long*)raw;
        for (int e = s0 + t; e < s1; e += 256) {
            int sr = (int)p[e], d = (int)p[E + e];
            int b = d >> 9;
            int r = atomicAdd(&lfill[b], 1);
            pbuf[gbase[b] + r] = ((uint32_t)(d & 511) << 17) | (uint32_t)sr;
        }
    }
}

// Pass D: per 512-node bucket: LDS hist + scan -> offsets; scatter srcs within the
// bucket's contiguous ~32KB window (L2-resident, dense writebacks).
__global__ __launch_bounds__(512) void fine_bucket(const uint32_t* __restrict__ pbuf,
                                                   const int* __restrict__ coff,
                                                   int* __restrict__ offsets,
                                                   int* __restrict__ srcs_sort, int N) {
    __shared__ int cnt[512], sc[512], fil[512];
    const int b = blockIdx.x, t = threadIdx.x;
    const int s = coff[b], e = coff[b + 1];
    cnt[t] = 0; fil[t] = 0;
    __syncthreads();
    for (int i = s + t; i < e; i += 512) atomicAdd(&cnt[pbuf[i] >> 17], 1);
    __syncthreads();
    sc[t] = cnt[t];
    __syncthreads();
    for (int off = 1; off < 512; off <<= 1) {
        int add = (t >= off) ? sc[t - off] : 0;
        __syncthreads();
        sc[t] += add;
        __syncthreads();
    }
    const int nb0 = b * 512;
    if (nb0 + t < N) offsets[nb0 + t] = s + sc[t] - cnt[t];
    for (int i = s + t; i < e; i += 512) {
        uint32_t p = pbuf[i];
        int dl = (int)(p >> 17);
        int sr = (int)(p & 0x1FFFFu);
        int pos = s + (sc[dl] - cnt[dl]) + atomicAdd(&fil[dl], 1);
        srcs_sort[pos] = sr;
    }
}

// ---------------- mean aggregation (bf16 in, bf16 out): one wave per node ----------------
template<int K>
__global__ void aggregate_kernel(const int* __restrict__ offsets, const int* __restrict__ srcs,
                                 const ushort* __restrict__ xb, ushort* __restrict__ meanb, int N) {
    int wave = threadIdx.x >> 6;
    int lane = threadIdx.x & 63;
    int node = blockIdx.x * 4 + wave;   // blockDim = 256
    if (node >= N) return;
    int s0 = offsets[node], s1 = offsets[node + 1];
    float inv = 1.0f / fmaxf((float)(s1 - s0), 1.0f);

    if (K == 64) {
        float a0 = 0.f, a1 = 0.f, a2 = 0.f, a3 = 0.f;
        for (int base = s0; base < s1; base += 64) {
            int cnt = min(64, s1 - base);
            int myidx = (base + lane < s1) ? srcs[base + lane] : 0;
            int j = 0;
            for (; j + 4 <= cnt; j += 4) {
                int sa = __shfl(myidx, j);
                int sb = __shfl(myidx, j + 1);
                int sc_ = __shfl(myidx, j + 2);
                int sd = __shfl(myidx, j + 3);
                float va = bf2f(xb[(size_t)sa * 64 + lane]);
                float vb = bf2f(xb[(size_t)sb * 64 + lane]);
                float vc = bf2f(xb[(size_t)sc_ * 64 + lane]);
                float vd = bf2f(xb[(size_t)sd * 64 + lane]);
                a0 += va; a1 += vb; a2 += vc; a3 += vd;
            }
            for (; j < cnt; j++) {
                int s = __shfl(myidx, j);
                a0 += bf2f(xb[(size_t)s * 64 + lane]);
            }
        }
        meanb[(size_t)node * 64 + lane] = f2bf((a0 + a1 + a2 + a3) * inv);
    } else {
        float x0 = 0.f, y0 = 0.f, x1 = 0.f, y1 = 0.f;
        float x2 = 0.f, y2 = 0.f, x3 = 0.f, y3 = 0.f;
        for (int base = s0; base < s1; base += 64) {
            int cnt = min(64, s1 - base);
            int myidx = (base + lane < s1) ? srcs[base + lane] : 0;
            int j = 0;
            for (; j + 4 <= cnt; j += 4) {
                int sa = __shfl(myidx, j);
                int sb = __shfl(myidx, j + 1);
                int sc_ = __shfl(myidx, j + 2);
                int sd = __shfl(myidx, j + 3);
                uint32_t ua = *(const uint32_t*)&xb[(size_t)sa * 128 + 2 * lane];
                uint32_t ub = *(const uint32_t*)&xb[(size_t)sb * 128 + 2 * lane];
                uint32_t uc = *(const uint32_t*)&xb[(size_t)sc_ * 128 + 2 * lane];
                uint32_t ud = *(const uint32_t*)&xb[(size_t)sd * 128 + 2 * lane];
                x0 += bflo(ua); y0 += bfhi(ua);
                x1 += bflo(ub); y1 += bfhi(ub);
                x2 += bflo(uc); y2 += bfhi(uc);
                x3 += bflo(ud); y3 += bfhi(ud);
            }
            for (; j < cnt; j++) {
                int s = __shfl(myidx, j);
                uint32_t u = *(const uint32_t*)&xb[(size_t)s * 128 + 2 * lane];
                x0 += bflo(u); y0 += bfhi(u);
            }
        }
        ushort o[2] = { f2bf((x0 + x1 + x2 + x3) * inv), f2bf((y0 + y1 + y2 + y3) * inv) };
        *(uint32_t*)&meanb[(size_t)node * 128 + 2 * lane] = *(const uint32_t*)o;
    }
}

// ---------------- MFMA SAGE linear: out = [mean|self] @ Wcat^T + bl ----------------
template<int K, bool RELU, bool OUT_BF16>
__global__ __launch_bounds__(256) void sage_gemm_mfma(
    const ushort* __restrict__ meanb, const ushort* __restrict__ selfb,
    const ushort* __restrict__ Wcat, const float* __restrict__ bl,
    void* __restrict__ outv, int N)
{
    const int KT = 2 * K;
    const int wave = threadIdx.x >> 6;
    const int lane = threadIdx.x & 63;
    const int lrow = lane & 15;
    const int lgrp = lane >> 4;
    const int n0 = blockIdx.x * 128 + wave * 32;

    f32x4 acc[2][8];
    #pragma unroll
    for (int h = 0; h < 2; h++)
        #pragma unroll
        for (int t = 0; t < 8; t++)
            acc[h][t] = (f32x4){0.f, 0.f, 0.f, 0.f};

    const int ar0 = min(n0 + lrow, N - 1);
    const int ar1 = min(n0 + 16 + lrow, N - 1);

    #pragma unroll
    for (int ks = 0; ks < KT; ks += 32) {
        const ushort* Ap = (ks < K) ? meanb : selfb;
        const int ac = (ks < K) ? ks : (ks - K);
        bf16x8 a0 = *(const bf16x8*)&Ap[(size_t)ar0 * K + ac + lgrp * 8];
        bf16x8 a1 = *(const bf16x8*)&Ap[(size_t)ar1 * K + ac + lgrp * 8];
        #pragma unroll
        for (int t = 0; t < 8; t++) {
            bf16x8 b = *(const bf16x8*)&Wcat[(size_t)(t * 16 + lrow) * KT + ks + lgrp * 8];
            acc[0][t] = __builtin_amdgcn_mfma_f32_16x16x32_bf16(a0, b, acc[0][t], 0, 0, 0);
            acc[1][t] = __builtin_amdgcn_mfma_f32_16x16x32_bf16(a1, b, acc[1][t], 0, 0, 0);
        }
    }

    #pragma unroll
    for (int t = 0; t < 8; t++) {
        int c = t * 16 + lrow;
        float bias = bl[c];
        #pragma unroll
        for (int h = 0; h < 2; h++) {
            #pragma unroll
            for (int r = 0; r < 4; r++) {
                int n = n0 + h * 16 + lgrp * 4 + r;
                if (n < N) {
                    float v = acc[h][t][r] + bias;
                    if (RELU) v = fmaxf(v, 0.0f);
                    if (OUT_BF16) ((ushort*)outv)[(size_t)n * 128 + c] = f2bf(v);
                    else         ((float*)outv)[(size_t)n * 128 + c] = v;
                }
            }
        }
    }
}

// ---------------- launch ----------------
extern "C" void kernel_launch(void* const* d_in, const int* in_sizes, int n_in,
                              void* d_out, int out_size, void* d_ws, size_t ws_size,
                              hipStream_t stream) {
    const float* x   = (const float*)d_in[0];
    const void*  er  = d_in[1];
    const float* Wl1 = (const float*)d_in[2];
    const float* bl1 = (const float*)d_in[3];
    const float* Wr1 = (const float*)d_in[4];
    const float* Wl2 = (const float*)d_in[5];
    const float* bl2 = (const float*)d_in[6];
    const float* Wr2 = (const float*)d_in[7];
    float* out = (float*)d_out;

    const int N = NN, E = EE;

    // workspace carve-up (512B aligned)
    char* ws = (char*)d_ws;
    size_t off = 0;
    auto carve = [&](size_t bytes) { char* p = ws + off; off += (bytes + 511) & ~(size_t)511; return p; };
    int*      flag      = (int*)     carve(4);
    int*      ccnt      = (int*)     carve((size_t)NBUCK * 4);
    int*      cfill     = (int*)     carve((size_t)NBUCK * 4);
    int*      coff      = (int*)     carve((size_t)(NBUCK + 1) * 4);
    uint32_t* pbuf      = (uint32_t*)carve((size_t)E * 4);
    int*      offsets   = (int*)     carve((size_t)(N + 1) * 4);
    int*      srcs_sort = (int*)     carve((size_t)E * 4);
    ushort*   xb        = (ushort*)  carve((size_t)N * 64 * 2);
    ushort*   meanb     = (ushort*)  carve((size_t)N * 128 * 2);
    ushort*   hb        = (ushort*)  carve((size_t)N * 128 * 2);
    ushort*   wc1       = (ushort*)  carve((size_t)128 * 128 * 2);
    ushort*   wc2       = (ushort*)  carve((size_t)128 * 256 * 2);
    (void)ws_size;

    hipMemsetAsync(flag, 0, 4, stream);
    hipMemsetAsync(ccnt, 0, (size_t)NBUCK * 4, stream);
    hipMemsetAsync(cfill, 0, (size_t)NBUCK * 4, stream);

    detect_kernel<<<16, 256, 0, stream>>>((const unsigned int*)er, flag);

    // bf16 conversions (independent of CSR build)
    cvt_f32_bf16<<<(N * 64 / 4 + 255) / 256, 256, 0, stream>>>(x, xb, N * 64 / 4);
    build_wcat<<<(128 * 128 + 255) / 256, 256, 0, stream>>>(Wl1, Wr1, wc1, 64);
    build_wcat<<<(128 * 256 + 255) / 256, 256, 0, stream>>>(Wl2, Wr2, wc2, 128);

    // CSR build: two-level partition with block-level reservation
    coarse_hist<<<512, 256, 0, stream>>>(er, flag, ccnt, E);
    coarse_scan<<<1, 256, 0, stream>>>(ccnt, coff, offsets, E);
    coarse_scatter2<<<CSB, 256, 0, stream>>>(er, flag, coff, cfill, pbuf, E);
    fine_bucket<<<NBUCK, 512, 0, stream>>>(pbuf, coff, offsets, srcs_sort, N);

    const int ab = (N + 3) / 4;                              // 25000 (4 waves/block)
    const int gb = (N + 127) / 128;                          // 782

    // layer 1
    aggregate_kernel<64><<<ab, 256, 0, stream>>>(offsets, srcs_sort, xb, meanb, N);
    sage_gemm_mfma<64, true, true><<<gb, 256, 0, stream>>>(meanb, xb, wc1, bl1, hb, N);

    // layer 2
    aggregate_kernel<128><<<ab, 256, 0, stream>>>(offsets, srcs_sort, hb, meanb, N);
    sage_gemm_mfma<128, false, false><<<gb, 256, 0, stream>>>(meanb, hb, wc2, bl2, out, N);
}

// Round 6
// 272.421 us; speedup vs baseline: 2.3496x; 1.0381x over previous
//
#include <hip/hip_runtime.h>
#include <hip/hip_bf16.h>
#include <stdint.h>

#define NN 100000
#define EE 1600000
#define NBUCK 196              // ceil(NN/512): buckets of 512 dst nodes
#define CSB 512                // coarse-scatter blocks

typedef __attribute__((ext_vector_type(4))) float f32x4;
typedef __attribute__((ext_vector_type(8))) short bf16x8;

__device__ inline ushort f2bf(float f) {
    union { float f; uint32_t u; } v; v.f = f;
    uint32_t u = v.u;
    uint32_t r = (u + 0x7fffu + ((u >> 16) & 1u)) >> 16;   // RNE
    return (ushort)r;
}
__device__ inline float bf2f(ushort h) {
    union { uint32_t u; float f; } v; v.u = ((uint32_t)h) << 16; return v.f;
}
__device__ inline float bflo(uint32_t u) {
    union { uint32_t u; float f; } v; v.u = u << 16; return v.f;
}
__device__ inline float bfhi(uint32_t u) {
    union { uint32_t u; float f; } v; v.u = u & 0xffff0000u; return v.f;
}

// ---------------- edge dtype detect ----------------
__global__ void detect_kernel(const unsigned int* raw, int* flag) {
    int i = blockIdx.x * blockDim.x + threadIdx.x;
    if (i < 4096) {
        if (raw[2 * i + 1] != 0u) atomicOr(flag, 1);
    }
}

// ---------------- dtype conversion passes ----------------
__global__ void cvt_f32_bf16(const float* __restrict__ in, ushort* __restrict__ out, int n4) {
    int i = blockIdx.x * blockDim.x + threadIdx.x;   // one float4 per thread
    if (i >= n4) return;
    float4 v = *(const float4*)&in[i * 4];
    ushort o[4] = { f2bf(v.x), f2bf(v.y), f2bf(v.z), f2bf(v.w) };
    *(uint64_t*)&out[i * 4] = *(const uint64_t*)o;
}

// Wcat[o][0..K) = Wl[o][:], Wcat[o][K..2K) = Wr[o][:]  (bf16)
__global__ void build_wcat(const float* __restrict__ Wl, const float* __restrict__ Wr,
                           ushort* __restrict__ Wcat, int K) {
    int t = blockIdx.x * blockDim.x + threadIdx.x;
    int KT = 2 * K;
    if (t >= 128 * KT) return;
    int o = t / KT, k = t % KT;
    float v = (k < K) ? Wl[o * K + k] : Wr[o * K + (k - K)];
    Wcat[o * KT + k] = f2bf(v);
}

// ---------------- CSR build: two-level partition (block-reserved) ----------------
__global__ __launch_bounds__(256) void coarse_hist(const void* raw, const int* flag,
                                                   int* ccnt, int E) {
    __shared__ int lh[NBUCK];
    for (int i = threadIdx.x; i < NBUCK; i += 256) lh[i] = 0;
    __syncthreads();
    int stride = gridDim.x * 256;
    if (*flag) {
        const int* p = (const int*)raw;
        for (int e = blockIdx.x * 256 + threadIdx.x; e < E; e += stride)
            atomicAdd(&lh[p[E + e] >> 9], 1);
    } else {
        const long long* p = (const long long*)raw;
        for (int e = blockIdx.x * 256 + threadIdx.x; e < E; e += stride)
            atomicAdd(&lh[((int)p[E + e]) >> 9], 1);
    }
    __syncthreads();
    for (int i = threadIdx.x; i < NBUCK; i += 256)
        if (lh[i]) atomicAdd(&ccnt[i], lh[i]);
}

__global__ void coarse_scan(const int* ccnt, int* coff, int* offsets, int E) {
    __shared__ int part[256];
    int t = threadIdx.x;
    int v[4]; int s = 0;
    #pragma unroll
    for (int j = 0; j < 4; j++) {
        int i = t * 4 + j;
        v[j] = (i < NBUCK) ? ccnt[i] : 0;
        s += v[j];
    }
    part[t] = s; __syncthreads();
    for (int off = 1; off < 256; off <<= 1) {
        int add = (t >= off) ? part[t - off] : 0;
        __syncthreads();
        part[t] += add;
        __syncthreads();
    }
    int run = part[t] - s;
    #pragma unroll
    for (int j = 0; j < 4; j++) {
        int i = t * 4 + j;
        if (i <= NBUCK) coff[i] = run;
        run += v[j];
    }
    if (t == 0) offsets[NN] = E;
}

__global__ __launch_bounds__(256) void coarse_scatter2(const void* raw, const int* flag,
                                                       const int* coff, int* cfill,
                                                       uint32_t* pbuf, int E) {
    __shared__ int lh[NBUCK];
    __shared__ int gbase[NBUCK];
    __shared__ int lfill[NBUCK];
    const int t = threadIdx.x;
    for (int i = t; i < NBUCK; i += 256) { lh[i] = 0; lfill[i] = 0; }
    __syncthreads();
    const int chunk = (E + (int)gridDim.x - 1) / (int)gridDim.x;
    const int s0 = blockIdx.x * chunk;
    const int s1 = min(E, s0 + chunk);
    const bool is32 = (*flag != 0);
    if (is32) {
        const int* p = (const int*)raw;
        for (int e = s0 + t; e < s1; e += 256) atomicAdd(&lh[p[E + e] >> 9], 1);
    } else {
        const long long* p = (const long long*)raw;
        for (int e = s0 + t; e < s1; e += 256) atomicAdd(&lh[((int)p[E + e]) >> 9], 1);
    }
    __syncthreads();
    for (int i = t; i < NBUCK; i += 256)
        gbase[i] = coff[i] + (lh[i] ? atomicAdd(&cfill[i], lh[i]) : 0);
    __syncthreads();
    if (is32) {
        const int* p = (const int*)raw;
        for (int e = s0 + t; e < s1; e += 256) {
            int sr = p[e], d = p[E + e];
            int b = d >> 9;
            int r = atomicAdd(&lfill[b], 1);
            pbuf[gbase[b] + r] = ((uint32_t)(d & 511) << 17) | (uint32_t)sr;
        }
    } else {
        const long long* p = (const long long*)raw;
        for (int e = s0 + t; e < s1; e += 256) {
            int sr = (int)p[e], d = (int)p[E + e];
            int b = d >> 9;
            int r = atomicAdd(&lfill[b], 1);
            pbuf[gbase[b] + r] = ((uint32_t)(d & 511) << 17) | (uint32_t)sr;
        }
    }
}

__global__ __launch_bounds__(512) void fine_bucket(const uint32_t* __restrict__ pbuf,
                                                   const int* __restrict__ coff,
                                                   int* __restrict__ offsets,
                                                   int* __restrict__ srcs_sort, int N) {
    __shared__ int cnt[512], sc[512], fil[512];
    const int b = blockIdx.x, t = threadIdx.x;
    const int s = coff[b], e = coff[b + 1];
    cnt[t] = 0; fil[t] = 0;
    __syncthreads();
    for (int i = s + t; i < e; i += 512) atomicAdd(&cnt[pbuf[i] >> 17], 1);
    __syncthreads();
    sc[t] = cnt[t];
    __syncthreads();
    for (int off = 1; off < 512; off <<= 1) {
        int add = (t >= off) ? sc[t - off] : 0;
        __syncthreads();
        sc[t] += add;
        __syncthreads();
    }
    const int nb0 = b * 512;
    if (nb0 + t < N) offsets[nb0 + t] = s + sc[t] - cnt[t];
    for (int i = s + t; i < e; i += 512) {
        uint32_t p = pbuf[i];
        int dl = (int)(p >> 17);
        int sr = (int)(p & 0x1FFFFu);
        int pos = s + (sc[dl] - cnt[dl]) + atomicAdd(&fil[dl], 1);
        srcs_sort[pos] = sr;
    }
}

// ---------------- mean aggregation (bf16 in, bf16 out): one wave per node ----------------
template<int K>
__global__ void aggregate_kernel(const int* __restrict__ offsets, const int* __restrict__ srcs,
                                 const ushort* __restrict__ xb, ushort* __restrict__ meanb, int N) {
    int wave = threadIdx.x >> 6;
    int lane = threadIdx.x & 63;
    int node = blockIdx.x * 4 + wave;   // blockDim = 256
    if (node >= N) return;
    int s0 = offsets[node], s1 = offsets[node + 1];
    float inv = 1.0f / fmaxf((float)(s1 - s0), 1.0f);

    if (K == 64) {
        float a0 = 0.f, a1 = 0.f, a2 = 0.f, a3 = 0.f;
        for (int base = s0; base < s1; base += 64) {
            int cnt = min(64, s1 - base);
            int myidx = (base + lane < s1) ? srcs[base + lane] : 0;
            int j = 0;
            for (; j + 4 <= cnt; j += 4) {
                int sa = __shfl(myidx, j);
                int sb = __shfl(myidx, j + 1);
                int sc_ = __shfl(myidx, j + 2);
                int sd = __shfl(myidx, j + 3);
                float va = bf2f(xb[(size_t)sa * 64 + lane]);
                float vb = bf2f(xb[(size_t)sb * 64 + lane]);
                float vc = bf2f(xb[(size_t)sc_ * 64 + lane]);
                float vd = bf2f(xb[(size_t)sd * 64 + lane]);
                a0 += va; a1 += vb; a2 += vc; a3 += vd;
            }
            for (; j < cnt; j++) {
                int s = __shfl(myidx, j);
                a0 += bf2f(xb[(size_t)s * 64 + lane]);
            }
        }
        meanb[(size_t)node * 64 + lane] = f2bf((a0 + a1 + a2 + a3) * inv);
    } else {
        float x0 = 0.f, y0 = 0.f, x1 = 0.f, y1 = 0.f;
        float x2 = 0.f, y2 = 0.f, x3 = 0.f, y3 = 0.f;
        for (int base = s0; base < s1; base += 64) {
            int cnt = min(64, s1 - base);
            int myidx = (base + lane < s1) ? srcs[base + lane] : 0;
            int j = 0;
            for (; j + 4 <= cnt; j += 4) {
                int sa = __shfl(myidx, j);
                int sb = __shfl(myidx, j + 1);
                int sc_ = __shfl(myidx, j + 2);
                int sd = __shfl(myidx, j + 3);
                uint32_t ua = *(const uint32_t*)&xb[(size_t)sa * 128 + 2 * lane];
                uint32_t ub = *(const uint32_t*)&xb[(size_t)sb * 128 + 2 * lane];
                uint32_t uc = *(const uint32_t*)&xb[(size_t)sc_ * 128 + 2 * lane];
                uint32_t ud = *(const uint32_t*)&xb[(size_t)sd * 128 + 2 * lane];
                x0 += bflo(ua); y0 += bfhi(ua);
                x1 += bflo(ub); y1 += bfhi(ub);
                x2 += bflo(uc); y2 += bfhi(uc);
                x3 += bflo(ud); y3 += bfhi(ud);
            }
            for (; j < cnt; j++) {
                int s = __shfl(myidx, j);
                uint32_t u = *(const uint32_t*)&xb[(size_t)s * 128 + 2 * lane];
                x0 += bflo(u); y0 += bfhi(u);
            }
        }
        ushort o[2] = { f2bf((x0 + x1 + x2 + x3) * inv), f2bf((y0 + y1 + y2 + y3) * inv) };
        *(uint32_t*)&meanb[(size_t)node * 128 + 2 * lane] = *(const uint32_t*)o;
    }
}

// ---------------- MFMA SAGE linear (swapped operands): out = [mean|self] @ Wcat^T + bl ----
// D = mfma(W_frag, X_frag): D col = node (lane&15), D rows = channels.
// Lane (lrow,lgrp) holds, per ct, channels ct*16+lgrp*4..+3 of node n0+lrow
// -> contiguous 16B (f32) / 8B (bf16) stores. Register double-buffered K-loop.
template<int K, bool RELU, bool OUT_BF16>
__global__ __launch_bounds__(256) void sage_gemm_mfma(
    const ushort* __restrict__ meanb, const ushort* __restrict__ selfb,
    const ushort* __restrict__ Wcat, const float* __restrict__ bl,
    void* __restrict__ outv, int N)
{
    const int KT = 2 * K;
    const int wave = threadIdx.x >> 6;
    const int lane = threadIdx.x & 63;
    const int lrow = lane & 15;
    const int lgrp = lane >> 4;
    const int n0 = blockIdx.x * 128 + wave * 32;

    f32x4 acc[2][8];
    #pragma unroll
    for (int h = 0; h < 2; h++)
        #pragma unroll
        for (int t = 0; t < 8; t++)
            acc[h][t] = (f32x4){0.f, 0.f, 0.f, 0.f};

    const int ar0 = min(n0 + lrow, N - 1);
    const int ar1 = min(n0 + 16 + lrow, N - 1);

    bf16x8 xc0, xc1, wc0, wc1, wc2, wc3, wc4, wc5, wc6, wc7;
    bf16x8 xn0, xn1, wn0, wn1, wn2, wn3, wn4, wn5, wn6, wn7;

#define LOADX(ks, d0, d1) { \
    const ushort* Ap_ = ((ks) < K) ? meanb : selfb; \
    const int ac_ = ((ks) < K) ? (ks) : ((ks) - K); \
    d0 = *(const bf16x8*)&Ap_[(size_t)ar0 * K + ac_ + lgrp * 8]; \
    d1 = *(const bf16x8*)&Ap_[(size_t)ar1 * K + ac_ + lgrp * 8]; }
#define LOADW(ks, w0_,w1_,w2_,w3_,w4_,w5_,w6_,w7_) { \
    const ushort* Wp_ = &Wcat[(size_t)lrow * KT + (ks) + lgrp * 8]; \
    w0_ = *(const bf16x8*)&Wp_[(size_t)(0*16) * KT]; \
    w1_ = *(const bf16x8*)&Wp_[(size_t)(1*16) * KT]; \
    w2_ = *(const bf16x8*)&Wp_[(size_t)(2*16) * KT]; \
    w3_ = *(const bf16x8*)&Wp_[(size_t)(3*16) * KT]; \
    w4_ = *(const bf16x8*)&Wp_[(size_t)(4*16) * KT]; \
    w5_ = *(const bf16x8*)&Wp_[(size_t)(5*16) * KT]; \
    w6_ = *(const bf16x8*)&Wp_[(size_t)(6*16) * KT]; \
    w7_ = *(const bf16x8*)&Wp_[(size_t)(7*16) * KT]; }
#define MFMA16(x0_, x1_, w0_,w1_,w2_,w3_,w4_,w5_,w6_,w7_) { \
    acc[0][0] = __builtin_amdgcn_mfma_f32_16x16x32_bf16(w0_, x0_, acc[0][0], 0, 0, 0); \
    acc[1][0] = __builtin_amdgcn_mfma_f32_16x16x32_bf16(w0_, x1_, acc[1][0], 0, 0, 0); \
    acc[0][1] = __builtin_amdgcn_mfma_f32_16x16x32_bf16(w1_, x0_, acc[0][1], 0, 0, 0); \
    acc[1][1] = __builtin_amdgcn_mfma_f32_16x16x32_bf16(w1_, x1_, acc[1][1], 0, 0, 0); \
    acc[0][2] = __builtin_amdgcn_mfma_f32_16x16x32_bf16(w2_, x0_, acc[0][2], 0, 0, 0); \
    acc[1][2] = __builtin_amdgcn_mfma_f32_16x16x32_bf16(w2_, x1_, acc[1][2], 0, 0, 0); \
    acc[0][3] = __builtin_amdgcn_mfma_f32_16x16x32_bf16(w3_, x0_, acc[0][3], 0, 0, 0); \
    acc[1][3] = __builtin_amdgcn_mfma_f32_16x16x32_bf16(w3_, x1_, acc[1][3], 0, 0, 0); \
    acc[0][4] = __builtin_amdgcn_mfma_f32_16x16x32_bf16(w4_, x0_, acc[0][4], 0, 0, 0); \
    acc[1][4] = __builtin_amdgcn_mfma_f32_16x16x32_bf16(w4_, x1_, acc[1][4], 0, 0, 0); \
    acc[0][5] = __builtin_amdgcn_mfma_f32_16x16x32_bf16(w5_, x0_, acc[0][5], 0, 0, 0); \
    acc[1][5] = __builtin_amdgcn_mfma_f32_16x16x32_bf16(w5_, x1_, acc[1][5], 0, 0, 0); \
    acc[0][6] = __builtin_amdgcn_mfma_f32_16x16x32_bf16(w6_, x0_, acc[0][6], 0, 0, 0); \
    acc[1][6] = __builtin_amdgcn_mfma_f32_16x16x32_bf16(w6_, x1_, acc[1][6], 0, 0, 0); \
    acc[0][7] = __builtin_amdgcn_mfma_f32_16x16x32_bf16(w7_, x0_, acc[0][7], 0, 0, 0); \
    acc[1][7] = __builtin_amdgcn_mfma_f32_16x16x32_bf16(w7_, x1_, acc[1][7], 0, 0, 0); }

    LOADX(0, xc0, xc1);
    LOADW(0, wc0, wc1, wc2, wc3, wc4, wc5, wc6, wc7);
    #pragma unroll
    for (int ks = 0; ks < KT; ks += 32) {
        if (ks + 32 < KT) {
            LOADX(ks + 32, xn0, xn1);
            LOADW(ks + 32, wn0, wn1, wn2, wn3, wn4, wn5, wn6, wn7);
        }
        MFMA16(xc0, xc1, wc0, wc1, wc2, wc3, wc4, wc5, wc6, wc7);
        if (ks + 32 < KT) {
            xc0 = xn0; xc1 = xn1;
            wc0 = wn0; wc1 = wn1; wc2 = wn2; wc3 = wn3;
            wc4 = wn4; wc5 = wn5; wc6 = wn6; wc7 = wn7;
        }
    }
#undef LOADX
#undef LOADW
#undef MFMA16

    const int nA = n0 + lrow;
    const int nB = n0 + 16 + lrow;
    #pragma unroll
    for (int t = 0; t < 8; t++) {
        float4 b4 = *(const float4*)&bl[t * 16 + lgrp * 4];
        #pragma unroll
        for (int h = 0; h < 2; h++) {
            int n = (h == 0) ? nA : nB;
            if (n >= N) continue;
            float v0 = acc[h][t][0] + b4.x;
            float v1 = acc[h][t][1] + b4.y;
            float v2 = acc[h][t][2] + b4.z;
            float v3 = acc[h][t][3] + b4.w;
            if (RELU) {
                v0 = fmaxf(v0, 0.f); v1 = fmaxf(v1, 0.f);
                v2 = fmaxf(v2, 0.f); v3 = fmaxf(v3, 0.f);
            }
            if (OUT_BF16) {
                ushort o[4] = { f2bf(v0), f2bf(v1), f2bf(v2), f2bf(v3) };
                *(uint64_t*)&((ushort*)outv)[(size_t)n * 128 + t * 16 + lgrp * 4] =
                    *(const uint64_t*)o;
            } else {
                float4 o = make_float4(v0, v1, v2, v3);
                *(float4*)&((float*)outv)[(size_t)n * 128 + t * 16 + lgrp * 4] = o;
            }
        }
    }
}

// ---------------- launch ----------------
extern "C" void kernel_launch(void* const* d_in, const int* in_sizes, int n_in,
                              void* d_out, int out_size, void* d_ws, size_t ws_size,
                              hipStream_t stream) {
    const float* x   = (const float*)d_in[0];
    const void*  er  = d_in[1];
    const float* Wl1 = (const float*)d_in[2];
    const float* bl1 = (const float*)d_in[3];
    const float* Wr1 = (const float*)d_in[4];
    const float* Wl2 = (const float*)d_in[5];
    const float* bl2 = (const float*)d_in[6];
    const float* Wr2 = (const float*)d_in[7];
    float* out = (float*)d_out;

    const int N = NN, E = EE;

    // workspace carve-up (512B aligned)
    char* ws = (char*)d_ws;
    size_t off = 0;
    auto carve = [&](size_t bytes) { char* p = ws + off; off += (bytes + 511) & ~(size_t)511; return p; };
    int*      flag      = (int*)     carve(4);
    int*      ccnt      = (int*)     carve((size_t)NBUCK * 4);
    int*      cfill     = (int*)     carve((size_t)NBUCK * 4);
    int*      coff      = (int*)     carve((size_t)(NBUCK + 1) * 4);
    uint32_t* pbuf      = (uint32_t*)carve((size_t)E * 4);
    int*      offsets   = (int*)     carve((size_t)(N + 1) * 4);
    int*      srcs_sort = (int*)     carve((size_t)E * 4);
    ushort*   xb        = (ushort*)  carve((size_t)N * 64 * 2);
    ushort*   meanb     = (ushort*)  carve((size_t)N * 128 * 2);
    ushort*   hb        = (ushort*)  carve((size_t)N * 128 * 2);
    ushort*   wc1       = (ushort*)  carve((size_t)128 * 128 * 2);
    ushort*   wc2       = (ushort*)  carve((size_t)128 * 256 * 2);
    (void)ws_size;

    hipMemsetAsync(flag, 0, 4, stream);
    hipMemsetAsync(ccnt, 0, (size_t)NBUCK * 4, stream);
    hipMemsetAsync(cfill, 0, (size_t)NBUCK * 4, stream);

    detect_kernel<<<16, 256, 0, stream>>>((const unsigned int*)er, flag);

    // bf16 conversions (independent of CSR build)
    cvt_f32_bf16<<<(N * 64 / 4 + 255) / 256, 256, 0, stream>>>(x, xb, N * 64 / 4);
    build_wcat<<<(128 * 128 + 255) / 256, 256, 0, stream>>>(Wl1, Wr1, wc1, 64);
    build_wcat<<<(128 * 256 + 255) / 256, 256, 0, stream>>>(Wl2, Wr2, wc2, 128);

    // CSR build: two-level partition with block-level reservation
    coarse_hist<<<512, 256, 0, stream>>>(er, flag, ccnt, E);
    coarse_scan<<<1, 256, 0, stream>>>(ccnt, coff, offsets, E);
    coarse_scatter2<<<CSB, 256, 0, stream>>>(er, flag, coff, cfill, pbuf, E);
    fine_bucket<<<NBUCK, 512, 0, stream>>>(pbuf, coff, offsets, srcs_sort, N);

    const int ab = (N + 3) / 4;                              // 25000 (4 waves/block)
    const int gb = (N + 127) / 128;                          // 782

    // layer 1
    aggregate_kernel<64><<<ab, 256, 0, stream>>>(offsets, srcs_sort, xb, meanb, N);
    sage_gemm_mfma<64, true, true><<<gb, 256, 0, stream>>>(meanb, xb, wc1, bl1, hb, N);

    // layer 2
    aggregate_kernel<128><<<ab, 256, 0, stream>>>(offsets, srcs_sort, hb, meanb, N);
    sage_gemm_mfma<128, false, false><<<gb, 256, 0, stream>>>(meanb, hb, wc2, bl2, out, N);
}

// Round 8
// 265.310 us; speedup vs baseline: 2.4125x; 1.0268x over previous
//
#include <hip/hip_runtime.h>
#include <hip/hip_bf16.h>
#include <stdint.h>

#define NN 100000
#define EE 1600000
#define NBUCK 196              // ceil(NN/512): buckets of 512 dst nodes
#define CSB 512                // coarse-scatter blocks

typedef __attribute__((ext_vector_type(4))) float f32x4;
typedef __attribute__((ext_vector_type(8))) short bf16x8;

__device__ inline ushort f2bf(float f) {
    union { float f; uint32_t u; } v; v.f = f;
    uint32_t u = v.u;
    uint32_t r = (u + 0x7fffu + ((u >> 16) & 1u)) >> 16;   // RNE
    return (ushort)r;
}
__device__ inline float bf2f(ushort h) {
    union { uint32_t u; float f; } v; v.u = ((uint32_t)h) << 16; return v.f;
}
__device__ inline float bflo(uint32_t u) {
    union { uint32_t u; float f; } v; v.u = u << 16; return v.f;
}
__device__ inline float bfhi(uint32_t u) {
    union { uint32_t u; float f; } v; v.u = u & 0xffff0000u; return v.f;
}

// ---------------- edge dtype detect ----------------
__global__ void detect_kernel(const unsigned int* raw, int* flag) {
    int i = blockIdx.x * blockDim.x + threadIdx.x;
    if (i < 4096) {
        if (raw[2 * i + 1] != 0u) atomicOr(flag, 1);
    }
}

// ---------------- dtype conversion passes ----------------
__global__ void cvt_f32_bf16(const float* __restrict__ in, ushort* __restrict__ out, int n4) {
    int i = blockIdx.x * blockDim.x + threadIdx.x;   // one float4 per thread
    if (i >= n4) return;
    float4 v = *(const float4*)&in[i * 4];
    ushort o[4] = { f2bf(v.x), f2bf(v.y), f2bf(v.z), f2bf(v.w) };
    *(uint64_t*)&out[i * 4] = *(const uint64_t*)o;
}

// Wcat[o][0..K) = Wl[o][:], Wcat[o][K..2K) = Wr[o][:]  (bf16)
__global__ void build_wcat(const float* __restrict__ Wl, const float* __restrict__ Wr,
                           ushort* __restrict__ Wcat, int K) {
    int t = blockIdx.x * blockDim.x + threadIdx.x;
    int KT = 2 * K;
    if (t >= 128 * KT) return;
    int o = t / KT, k = t % KT;
    float v = (k < K) ? Wl[o * K + k] : Wr[o * K + (k - K)];
    Wcat[o * KT + k] = f2bf(v);
}

// ---------------- CSR build: two-level partition (block-reserved) ----------------
__global__ __launch_bounds__(256) void coarse_hist(const void* raw, const int* flag,
                                                   int* ccnt, int E) {
    __shared__ int lh[NBUCK];
    for (int i = threadIdx.x; i < NBUCK; i += 256) lh[i] = 0;
    __syncthreads();
    int stride = gridDim.x * 256;
    if (*flag) {
        const int* p = (const int*)raw;
        for (int e = blockIdx.x * 256 + threadIdx.x; e < E; e += stride)
            atomicAdd(&lh[p[E + e] >> 9], 1);
    } else {
        const long long* p = (const long long*)raw;
        for (int e = blockIdx.x * 256 + threadIdx.x; e < E; e += stride)
            atomicAdd(&lh[((int)p[E + e]) >> 9], 1);
    }
    __syncthreads();
    for (int i = threadIdx.x; i < NBUCK; i += 256)
        if (lh[i]) atomicAdd(&ccnt[i], lh[i]);
}

__global__ void coarse_scan(const int* ccnt, int* coff, int* offsets, int E) {
    __shared__ int part[256];
    int t = threadIdx.x;
    int v[4]; int s = 0;
    #pragma unroll
    for (int j = 0; j < 4; j++) {
        int i = t * 4 + j;
        v[j] = (i < NBUCK) ? ccnt[i] : 0;
        s += v[j];
    }
    part[t] = s; __syncthreads();
    for (int off = 1; off < 256; off <<= 1) {
        int add = (t >= off) ? part[t - off] : 0;
        __syncthreads();
        part[t] += add;
        __syncthreads();
    }
    int run = part[t] - s;
    #pragma unroll
    for (int j = 0; j < 4; j++) {
        int i = t * 4 + j;
        if (i <= NBUCK) coff[i] = run;
        run += v[j];
    }
    if (t == 0) offsets[NN] = E;
}

__global__ __launch_bounds__(256) void coarse_scatter2(const void* raw, const int* flag,
                                                       const int* coff, int* cfill,
                                                       uint32_t* pbuf, int E) {
    __shared__ int lh[NBUCK];
    __shared__ int gbase[NBUCK];
    __shared__ int lfill[NBUCK];
    const int t = threadIdx.x;
    for (int i = t; i < NBUCK; i += 256) { lh[i] = 0; lfill[i] = 0; }
    __syncthreads();
    const int chunk = (E + (int)gridDim.x - 1) / (int)gridDim.x;
    const int s0 = blockIdx.x * chunk;
    const int s1 = min(E, s0 + chunk);
    const bool is32 = (*flag != 0);
    if (is32) {
        const int* p = (const int*)raw;
        for (int e = s0 + t; e < s1; e += 256) atomicAdd(&lh[p[E + e] >> 9], 1);
    } else {
        const long long* p = (const long long*)raw;
        for (int e = s0 + t; e < s1; e += 256) atomicAdd(&lh[((int)p[E + e]) >> 9], 1);
    }
    __syncthreads();
    for (int i = t; i < NBUCK; i += 256)
        gbase[i] = coff[i] + (lh[i] ? atomicAdd(&cfill[i], lh[i]) : 0);
    __syncthreads();
    if (is32) {
        const int* p = (const int*)raw;
        for (int e = s0 + t; e < s1; e += 256) {
            int sr = p[e], d = p[E + e];
            int b = d >> 9;
            int r = atomicAdd(&lfill[b], 1);
            pbuf[gbase[b] + r] = ((uint32_t)(d & 511) << 17) | (uint32_t)sr;
        }
    } else {
        const long long* p = (const long long*)raw;
        for (int e = s0 + t; e < s1; e += 256) {
            int sr = (int)p[e], d = (int)p[E + e];
            int b = d >> 9;
            int r = atomicAdd(&lfill[b], 1);
            pbuf[gbase[b] + r] = ((uint32_t)(d & 511) << 17) | (uint32_t)sr;
        }
    }
}

__global__ __launch_bounds__(512) void fine_bucket(const uint32_t* __restrict__ pbuf,
                                                   const int* __restrict__ coff,
                                                   int* __restrict__ offsets,
                                                   int* __restrict__ srcs_sort, int N) {
    __shared__ int cnt[512], sc[512], fil[512];
    const int b = blockIdx.x, t = threadIdx.x;
    const int s = coff[b], e = coff[b + 1];
    cnt[t] = 0; fil[t] = 0;
    __syncthreads();
    for (int i = s + t; i < e; i += 512) atomicAdd(&cnt[pbuf[i] >> 17], 1);
    __syncthreads();
    sc[t] = cnt[t];
    __syncthreads();
    for (int off = 1; off < 512; off <<= 1) {
        int add = (t >= off) ? sc[t - off] : 0;
        __syncthreads();
        sc[t] += add;
        __syncthreads();
    }
    const int nb0 = b * 512;
    if (nb0 + t < N) offsets[nb0 + t] = s + sc[t] - cnt[t];
    for (int i = s + t; i < e; i += 512) {
        uint32_t p = pbuf[i];
        int dl = (int)(p >> 17);
        int sr = (int)(p & 0x1FFFFu);
        int pos = s + (sc[dl] - cnt[dl]) + atomicAdd(&fil[dl], 1);
        srcs_sort[pos] = sr;
    }
}

// ---------------- mean aggregation: one wave per node, TWO edges per iteration ----
// Lanes 0-31 cover edge A's full row with 8B/4B loads; lanes 32-63 cover edge B.
// Index broadcast via __shfl(myidx, j+half); halves combined via shfl_xor(32).
// NOTE: tail shfl is hoisted OUT of the divergent `half==0` branch — a shfl
// inside that branch reads from inactive source lanes (UB on wave64).
template<int K>
__global__ void aggregate_kernel(const int* __restrict__ offsets, const int* __restrict__ srcs,
                                 const ushort* __restrict__ xb, ushort* __restrict__ meanb, int N) {
    const int wave = threadIdx.x >> 6;
    const int lane = threadIdx.x & 63;
    const int half = lane >> 5;          // which edge of the pair
    const int sl   = lane & 31;          // channel-chunk index
    int node = blockIdx.x * 4 + wave;    // blockDim = 256
    if (node >= N) return;
    int s0 = offsets[node], s1 = offsets[node + 1];
    float inv = 1.0f / fmaxf((float)(s1 - s0), 1.0f);

    if (K == 64) {
        // lane covers channels 2sl..2sl+1 (uint32 = 2 bf16); 32 lanes x 4B = 128B row
        float ax0=0.f, ay0=0.f, ax1=0.f, ay1=0.f, ax2=0.f, ay2=0.f, ax3=0.f, ay3=0.f;
        for (int base = s0; base < s1; base += 64) {
            int cnt = min(64, s1 - base);
            int myidx = (base + lane < s1) ? srcs[base + lane] : 0;
            int j = 0;
            for (; j + 8 <= cnt; j += 8) {      // 4 pairs = 8 edges
                int sA = __shfl(myidx, j + half);
                int sB = __shfl(myidx, j + 2 + half);
                int sC = __shfl(myidx, j + 4 + half);
                int sD = __shfl(myidx, j + 6 + half);
                uint32_t uA = *(const uint32_t*)&xb[(size_t)sA * 64 + sl * 2];
                uint32_t uB = *(const uint32_t*)&xb[(size_t)sB * 64 + sl * 2];
                uint32_t uC = *(const uint32_t*)&xb[(size_t)sC * 64 + sl * 2];
                uint32_t uD = *(const uint32_t*)&xb[(size_t)sD * 64 + sl * 2];
                ax0 += bflo(uA); ay0 += bfhi(uA);
                ax1 += bflo(uB); ay1 += bfhi(uB);
                ax2 += bflo(uC); ay2 += bfhi(uC);
                ax3 += bflo(uD); ay3 += bfhi(uD);
            }
            for (; j + 2 <= cnt; j += 2) {      // pair tail (uniform branch)
                int s = __shfl(myidx, j + half);
                uint32_t u = *(const uint32_t*)&xb[(size_t)s * 64 + sl * 2];
                ax0 += bflo(u); ay0 += bfhi(u);
            }
            // odd tail: shfl executed by ALL lanes (j is wave-uniform), consumed by half 0
            int st = __shfl(myidx, j & 63);
            if (j < cnt && half == 0) {
                uint32_t u = *(const uint32_t*)&xb[(size_t)st * 64 + sl * 2];
                ax0 += bflo(u); ay0 += bfhi(u);
            }
        }
        float ax = ax0 + ax1 + ax2 + ax3;
        float ay = ay0 + ay1 + ay2 + ay3;
        ax += __shfl_xor(ax, 32);
        ay += __shfl_xor(ay, 32);
        if (half == 0) {
            ushort o[2] = { f2bf(ax * inv), f2bf(ay * inv) };
            *(uint32_t*)&meanb[(size_t)node * 64 + sl * 2] = *(const uint32_t*)o;
        }
    } else {
        // lane covers channels 4sl..4sl+3 (uint2 = 4 bf16); 32 lanes x 8B = 256B row
        float a0=0.f, a1=0.f, a2=0.f, a3=0.f;
        float b0=0.f, b1=0.f, b2=0.f, b3=0.f;
        float c0=0.f, c1=0.f, c2=0.f, c3=0.f;
        float d0=0.f, d1=0.f, d2=0.f, d3=0.f;
        for (int base = s0; base < s1; base += 64) {
            int cnt = min(64, s1 - base);
            int myidx = (base + lane < s1) ? srcs[base + lane] : 0;
            int j = 0;
            for (; j + 8 <= cnt; j += 8) {      // 4 pairs = 8 edges
                int sA = __shfl(myidx, j + half);
                int sB = __shfl(myidx, j + 2 + half);
                int sC = __shfl(myidx, j + 4 + half);
                int sD = __shfl(myidx, j + 6 + half);
                uint2 uA = *(const uint2*)&xb[(size_t)sA * 128 + sl * 4];
                uint2 uB = *(const uint2*)&xb[(size_t)sB * 128 + sl * 4];
                uint2 uC = *(const uint2*)&xb[(size_t)sC * 128 + sl * 4];
                uint2 uD = *(const uint2*)&xb[(size_t)sD * 128 + sl * 4];
                a0 += bflo(uA.x); a1 += bfhi(uA.x); a2 += bflo(uA.y); a3 += bfhi(uA.y);
                b0 += bflo(uB.x); b1 += bfhi(uB.x); b2 += bflo(uB.y); b3 += bfhi(uB.y);
                c0 += bflo(uC.x); c1 += bfhi(uC.x); c2 += bflo(uC.y); c3 += bfhi(uC.y);
                d0 += bflo(uD.x); d1 += bfhi(uD.x); d2 += bflo(uD.y); d3 += bfhi(uD.y);
            }
            for (; j + 2 <= cnt; j += 2) {      // pair tail (uniform branch)
                int s = __shfl(myidx, j + half);
                uint2 u = *(const uint2*)&xb[(size_t)s * 128 + sl * 4];
                a0 += bflo(u.x); a1 += bfhi(u.x); a2 += bflo(u.y); a3 += bfhi(u.y);
            }
            // odd tail: shfl hoisted out of divergent branch
            int st = __shfl(myidx, j & 63);
            if (j < cnt && half == 0) {
                uint2 u = *(const uint2*)&xb[(size_t)st * 128 + sl * 4];
                a0 += bflo(u.x); a1 += bfhi(u.x); a2 += bflo(u.y); a3 += bfhi(u.y);
            }
        }
        float v0 = a0 + b0 + c0 + d0;
        float v1 = a1 + b1 + c1 + d1;
        float v2 = a2 + b2 + c2 + d2;
        float v3 = a3 + b3 + c3 + d3;
        v0 += __shfl_xor(v0, 32);
        v1 += __shfl_xor(v1, 32);
        v2 += __shfl_xor(v2, 32);
        v3 += __shfl_xor(v3, 32);
        if (half == 0) {
            ushort o[4] = { f2bf(v0 * inv), f2bf(v1 * inv), f2bf(v2 * inv), f2bf(v3 * inv) };
            *(uint64_t*)&meanb[(size_t)node * 128 + sl * 4] = *(const uint64_t*)o;
        }
    }
}

// ---------------- MFMA SAGE linear (swapped operands): out = [mean|self] @ Wcat^T + bl ----
template<int K, bool RELU, bool OUT_BF16>
__global__ __launch_bounds__(256) void sage_gemm_mfma(
    const ushort* __restrict__ meanb, const ushort* __restrict__ selfb,
    const ushort* __restrict__ Wcat, const float* __restrict__ bl,
    void* __restrict__ outv, int N)
{
    const int KT = 2 * K;
    const int wave = threadIdx.x >> 6;
    const int lane = threadIdx.x & 63;
    const int lrow = lane & 15;
    const int lgrp = lane >> 4;
    const int n0 = blockIdx.x * 128 + wave * 32;

    f32x4 acc[2][8];
    #pragma unroll
    for (int h = 0; h < 2; h++)
        #pragma unroll
        for (int t = 0; t < 8; t++)
            acc[h][t] = (f32x4){0.f, 0.f, 0.f, 0.f};

    const int ar0 = min(n0 + lrow, N - 1);
    const int ar1 = min(n0 + 16 + lrow, N - 1);

    bf16x8 xc0, xc1, wc0, wc1, wc2, wc3, wc4, wc5, wc6, wc7;
    bf16x8 xn0, xn1, wn0, wn1, wn2, wn3, wn4, wn5, wn6, wn7;

#define LOADX(ks, d0, d1) { \
    const ushort* Ap_ = ((ks) < K) ? meanb : selfb; \
    const int ac_ = ((ks) < K) ? (ks) : ((ks) - K); \
    d0 = *(const bf16x8*)&Ap_[(size_t)ar0 * K + ac_ + lgrp * 8]; \
    d1 = *(const bf16x8*)&Ap_[(size_t)ar1 * K + ac_ + lgrp * 8]; }
#define LOADW(ks, w0_,w1_,w2_,w3_,w4_,w5_,w6_,w7_) { \
    const ushort* Wp_ = &Wcat[(size_t)lrow * KT + (ks) + lgrp * 8]; \
    w0_ = *(const bf16x8*)&Wp_[(size_t)(0*16) * KT]; \
    w1_ = *(const bf16x8*)&Wp_[(size_t)(1*16) * KT]; \
    w2_ = *(const bf16x8*)&Wp_[(size_t)(2*16) * KT]; \
    w3_ = *(const bf16x8*)&Wp_[(size_t)(3*16) * KT]; \
    w4_ = *(const bf16x8*)&Wp_[(size_t)(4*16) * KT]; \
    w5_ = *(const bf16x8*)&Wp_[(size_t)(5*16) * KT]; \
    w6_ = *(const bf16x8*)&Wp_[(size_t)(6*16) * KT]; \
    w7_ = *(const bf16x8*)&Wp_[(size_t)(7*16) * KT]; }
#define MFMA16(x0_, x1_, w0_,w1_,w2_,w3_,w4_,w5_,w6_,w7_) { \
    acc[0][0] = __builtin_amdgcn_mfma_f32_16x16x32_bf16(w0_, x0_, acc[0][0], 0, 0, 0); \
    acc[1][0] = __builtin_amdgcn_mfma_f32_16x16x32_bf16(w0_, x1_, acc[1][0], 0, 0, 0); \
    acc[0][1] = __builtin_amdgcn_mfma_f32_16x16x32_bf16(w1_, x0_, acc[0][1], 0, 0, 0); \
    acc[1][1] = __builtin_amdgcn_mfma_f32_16x16x32_bf16(w1_, x1_, acc[1][1], 0, 0, 0); \
    acc[0][2] = __builtin_amdgcn_mfma_f32_16x16x32_bf16(w2_, x0_, acc[0][2], 0, 0, 0); \
    acc[1][2] = __builtin_amdgcn_mfma_f32_16x16x32_bf16(w2_, x1_, acc[1][2], 0, 0, 0); \
    acc[0][3] = __builtin_amdgcn_mfma_f32_16x16x32_bf16(w3_, x0_, acc[0][3], 0, 0, 0); \
    acc[1][3] = __builtin_amdgcn_mfma_f32_16x16x32_bf16(w3_, x1_, acc[1][3], 0, 0, 0); \
    acc[0][4] = __builtin_amdgcn_mfma_f32_16x16x32_bf16(w4_, x0_, acc[0][4], 0, 0, 0); \
    acc[1][4] = __builtin_amdgcn_mfma_f32_16x16x32_bf16(w4_, x1_, acc[1][4], 0, 0, 0); \
    acc[0][5] = __builtin_amdgcn_mfma_f32_16x16x32_bf16(w5_, x0_, acc[0][5], 0, 0, 0); \
    acc[1][5] = __builtin_amdgcn_mfma_f32_16x16x32_bf16(w5_, x1_, acc[1][5], 0, 0, 0); \
    acc[0][6] = __builtin_amdgcn_mfma_f32_16x16x32_bf16(w6_, x0_, acc[0][6], 0, 0, 0); \
    acc[1][6] = __builtin_amdgcn_mfma_f32_16x16x32_bf16(w6_, x1_, acc[1][6], 0, 0, 0); \
    acc[0][7] = __builtin_amdgcn_mfma_f32_16x16x32_bf16(w7_, x0_, acc[0][7], 0, 0, 0); \
    acc[1][7] = __builtin_amdgcn_mfma_f32_16x16x32_bf16(w7_, x1_, acc[1][7], 0, 0, 0); }

    LOADX(0, xc0, xc1);
    LOADW(0, wc0, wc1, wc2, wc3, wc4, wc5, wc6, wc7);
    #pragma unroll
    for (int ks = 0; ks < KT; ks += 32) {
        if (ks + 32 < KT) {
            LOADX(ks + 32, xn0, xn1);
            LOADW(ks + 32, wn0, wn1, wn2, wn3, wn4, wn5, wn6, wn7);
        }
        MFMA16(xc0, xc1, wc0, wc1, wc2, wc3, wc4, wc5, wc6, wc7);
        if (ks + 32 < KT) {
            xc0 = xn0; xc1 = xn1;
            wc0 = wn0; wc1 = wn1; wc2 = wn2; wc3 = wn3;
            wc4 = wn4; wc5 = wn5; wc6 = wn6; wc7 = wn7;
        }
    }
#undef LOADX
#undef LOADW
#undef MFMA16

    const int nA = n0 + lrow;
    const int nB = n0 + 16 + lrow;
    #pragma unroll
    for (int t = 0; t < 8; t++) {
        float4 b4 = *(const float4*)&bl[t * 16 + lgrp * 4];
        #pragma unroll
        for (int h = 0; h < 2; h++) {
            int n = (h == 0) ? nA : nB;
            if (n >= N) continue;
            float v0 = acc[h][t][0] + b4.x;
            float v1 = acc[h][t][1] + b4.y;
            float v2 = acc[h][t][2] + b4.z;
            float v3 = acc[h][t][3] + b4.w;
            if (RELU) {
                v0 = fmaxf(v0, 0.f); v1 = fmaxf(v1, 0.f);
                v2 = fmaxf(v2, 0.f); v3 = fmaxf(v3, 0.f);
            }
            if (OUT_BF16) {
                ushort o[4] = { f2bf(v0), f2bf(v1), f2bf(v2), f2bf(v3) };
                *(uint64_t*)&((ushort*)outv)[(size_t)n * 128 + t * 16 + lgrp * 4] =
                    *(const uint64_t*)o;
            } else {
                float4 o = make_float4(v0, v1, v2, v3);
                *(float4*)&((float*)outv)[(size_t)n * 128 + t * 16 + lgrp * 4] = o;
            }
        }
    }
}

// ---------------- launch ----------------
extern "C" void kernel_launch(void* const* d_in, const int* in_sizes, int n_in,
                              void* d_out, int out_size, void* d_ws, size_t ws_size,
                              hipStream_t stream) {
    const float* x   = (const float*)d_in[0];
    const void*  er  = d_in[1];
    const float* Wl1 = (const float*)d_in[2];
    const float* bl1 = (const float*)d_in[3];
    const float* Wr1 = (const float*)d_in[4];
    const float* Wl2 = (const float*)d_in[5];
    const float* bl2 = (const float*)d_in[6];
    const float* Wr2 = (const float*)d_in[7];
    float* out = (float*)d_out;

    const int N = NN, E = EE;

    // workspace carve-up (512B aligned)
    char* ws = (char*)d_ws;
    size_t off = 0;
    auto carve = [&](size_t bytes) { char* p = ws + off; off += (bytes + 511) & ~(size_t)511; return p; };
    int*      flag      = (int*)     carve(4);
    int*      ccnt      = (int*)     carve((size_t)NBUCK * 4);
    int*      cfill     = (int*)     carve((size_t)NBUCK * 4);
    int*      coff      = (int*)     carve((size_t)(NBUCK + 1) * 4);
    uint32_t* pbuf      = (uint32_t*)carve((size_t)E * 4);
    int*      offsets   = (int*)     carve((size_t)(N + 1) * 4);
    int*      srcs_sort = (int*)     carve((size_t)E * 4);
    ushort*   xb        = (ushort*)  carve((size_t)N * 64 * 2);
    ushort*   meanb     = (ushort*)  carve((size_t)N * 128 * 2);
    ushort*   hb        = (ushort*)  carve((size_t)N * 128 * 2);
    ushort*   wc1       = (ushort*)  carve((size_t)128 * 128 * 2);
    ushort*   wc2       = (ushort*)  carve((size_t)128 * 256 * 2);
    (void)ws_size;

    hipMemsetAsync(flag, 0, 4, stream);
    hipMemsetAsync(ccnt, 0, (size_t)NBUCK * 4, stream);
    hipMemsetAsync(cfill, 0, (size_t)NBUCK * 4, stream);

    detect_kernel<<<16, 256, 0, stream>>>((const unsigned int*)er, flag);

    // bf16 conversions (independent of CSR build)
    cvt_f32_bf16<<<(N * 64 / 4 + 255) / 256, 256, 0, stream>>>(x, xb, N * 64 / 4);
    build_wcat<<<(128 * 128 + 255) / 256, 256, 0, stream>>>(Wl1, Wr1, wc1, 64);
    build_wcat<<<(128 * 256 + 255) / 256, 256, 0, stream>>>(Wl2, Wr2, wc2, 128);

    // CSR build: two-level partition with block-level reservation
    coarse_hist<<<512, 256, 0, stream>>>(er, flag, ccnt, E);
    coarse_scan<<<1, 256, 0, stream>>>(ccnt, coff, offsets, E);
    coarse_scatter2<<<CSB, 256, 0, stream>>>(er, flag, coff, cfill, pbuf, E);
    fine_bucket<<<NBUCK, 512, 0, stream>>>(pbuf, coff, offsets, srcs_sort, N);

    const int ab = (N + 3) / 4;                              // 25000 (4 waves/block)
    const int gb = (N + 127) / 128;                          // 782

    // layer 1
    aggregate_kernel<64><<<ab, 256, 0, stream>>>(offsets, srcs_sort, xb, meanb, N);
    sage_gemm_mfma<64, true, true><<<gb, 256, 0, stream>>>(meanb, xb, wc1, bl1, hb, N);

    // layer 2
    aggregate_kernel<128><<<ab, 256, 0, stream>>>(offsets, srcs_sort, hb, meanb, N);
    sage_gemm_mfma<128, false, false><<<gb, 256, 0, stream>>>(meanb, hb, wc2, bl2, out, N);
}

// Round 9
// 218.667 us; speedup vs baseline: 2.9272x; 1.2133x over previous
//
#include <hip/hip_runtime.h>
#include <hip/hip_bf16.h>
#include <stdint.h>

#define NN 100000
#define EE 1600000
#define NBUCK 196              // ceil(NN/512): buckets of 512 dst nodes
#define CSB 512                // coarse-scatter blocks

typedef __attribute__((ext_vector_type(4))) float f32x4;
typedef __attribute__((ext_vector_type(8))) short bf16x8;

__device__ inline ushort f2bf(float f) {
    union { float f; uint32_t u; } v; v.f = f;
    uint32_t u = v.u;
    uint32_t r = (u + 0x7fffu + ((u >> 16) & 1u)) >> 16;   // RNE
    return (ushort)r;
}
__device__ inline float bflo(uint32_t u) {
    union { uint32_t u; float f; } v; v.u = u << 16; return v.f;
}
__device__ inline float bfhi(uint32_t u) {
    union { uint32_t u; float f; } v; v.u = u & 0xffff0000u; return v.f;
}

// ---------------- edge dtype detect ----------------
__global__ void detect_kernel(const unsigned int* raw, int* flag) {
    int i = blockIdx.x * blockDim.x + threadIdx.x;
    if (i < 4096) {
        if (raw[2 * i + 1] != 0u) atomicOr(flag, 1);
    }
}

// ---------------- dtype conversion passes ----------------
__global__ void cvt_f32_bf16(const float* __restrict__ in, ushort* __restrict__ out, int n4) {
    int i = blockIdx.x * blockDim.x + threadIdx.x;   // one float4 per thread
    if (i >= n4) return;
    float4 v = *(const float4*)&in[i * 4];
    ushort o[4] = { f2bf(v.x), f2bf(v.y), f2bf(v.z), f2bf(v.w) };
    *(uint64_t*)&out[i * 4] = *(const uint64_t*)o;
}

// Wcat[o][0..K) = Wl[o][:], Wcat[o][K..2K) = Wr[o][:]  (bf16)
__global__ void build_wcat(const float* __restrict__ Wl, const float* __restrict__ Wr,
                           ushort* __restrict__ Wcat, int K) {
    int t = blockIdx.x * blockDim.x + threadIdx.x;
    int KT = 2 * K;
    if (t >= 128 * KT) return;
    int o = t / KT, k = t % KT;
    float v = (k < K) ? Wl[o * K + k] : Wr[o * K + (k - K)];
    Wcat[o * KT + k] = f2bf(v);
}

// ---------------- CSR build: two-level partition (block-reserved) ----------------
__global__ __launch_bounds__(256) void coarse_hist(const void* raw, const int* flag,
                                                   int* ccnt, int E) {
    __shared__ int lh[NBUCK];
    for (int i = threadIdx.x; i < NBUCK; i += 256) lh[i] = 0;
    __syncthreads();
    int stride = gridDim.x * 256;
    if (*flag) {
        const int* p = (const int*)raw;
        for (int e = blockIdx.x * 256 + threadIdx.x; e < E; e += stride)
            atomicAdd(&lh[p[E + e] >> 9], 1);
    } else {
        const long long* p = (const long long*)raw;
        for (int e = blockIdx.x * 256 + threadIdx.x; e < E; e += stride)
            atomicAdd(&lh[((int)p[E + e]) >> 9], 1);
    }
    __syncthreads();
    for (int i = threadIdx.x; i < NBUCK; i += 256)
        if (lh[i]) atomicAdd(&ccnt[i], lh[i]);
}

__global__ void coarse_scan(const int* ccnt, int* coff, int* offsets, int E) {
    __shared__ int part[256];
    int t = threadIdx.x;
    int v[4]; int s = 0;
    #pragma unroll
    for (int j = 0; j < 4; j++) {
        int i = t * 4 + j;
        v[j] = (i < NBUCK) ? ccnt[i] : 0;
        s += v[j];
    }
    part[t] = s; __syncthreads();
    for (int off = 1; off < 256; off <<= 1) {
        int add = (t >= off) ? part[t - off] : 0;
        __syncthreads();
        part[t] += add;
        __syncthreads();
    }
    int run = part[t] - s;
    #pragma unroll
    for (int j = 0; j < 4; j++) {
        int i = t * 4 + j;
        if (i <= NBUCK) coff[i] = run;
        run += v[j];
    }
    if (t == 0) offsets[NN] = E;
}

__global__ __launch_bounds__(256) void coarse_scatter2(const void* raw, const int* flag,
                                                       const int* coff, int* cfill,
                                                       uint32_t* pbuf, int E) {
    __shared__ int lh[NBUCK];
    __shared__ int gbase[NBUCK];
    __shared__ int lfill[NBUCK];
    const int t = threadIdx.x;
    for (int i = t; i < NBUCK; i += 256) { lh[i] = 0; lfill[i] = 0; }
    __syncthreads();
    const int chunk = (E + (int)gridDim.x - 1) / (int)gridDim.x;
    const int s0 = blockIdx.x * chunk;
    const int s1 = min(E, s0 + chunk);
    const bool is32 = (*flag != 0);
    if (is32) {
        const int* p = (const int*)raw;
        for (int e = s0 + t; e < s1; e += 256) atomicAdd(&lh[p[E + e] >> 9], 1);
    } else {
        const long long* p = (const long long*)raw;
        for (int e = s0 + t; e < s1; e += 256) atomicAdd(&lh[((int)p[E + e]) >> 9], 1);
    }
    __syncthreads();
    for (int i = t; i < NBUCK; i += 256)
        gbase[i] = coff[i] + (lh[i] ? atomicAdd(&cfill[i], lh[i]) : 0);
    __syncthreads();
    if (is32) {
        const int* p = (const int*)raw;
        for (int e = s0 + t; e < s1; e += 256) {
            int sr = p[e], d = p[E + e];
            int b = d >> 9;
            int r = atomicAdd(&lfill[b], 1);
            pbuf[gbase[b] + r] = ((uint32_t)(d & 511) << 17) | (uint32_t)sr;
        }
    } else {
        const long long* p = (const long long*)raw;
        for (int e = s0 + t; e < s1; e += 256) {
            int sr = (int)p[e], d = (int)p[E + e];
            int b = d >> 9;
            int r = atomicAdd(&lfill[b], 1);
            pbuf[gbase[b] + r] = ((uint32_t)(d & 511) << 17) | (uint32_t)sr;
        }
    }
}

__global__ __launch_bounds__(512) void fine_bucket(const uint32_t* __restrict__ pbuf,
                                                   const int* __restrict__ coff,
                                                   int* __restrict__ offsets,
                                                   int* __restrict__ srcs_sort, int N) {
    __shared__ int cnt[512], sc[512], fil[512];
    const int b = blockIdx.x, t = threadIdx.x;
    const int s = coff[b], e = coff[b + 1];
    cnt[t] = 0; fil[t] = 0;
    __syncthreads();
    for (int i = s + t; i < e; i += 512) atomicAdd(&cnt[pbuf[i] >> 17], 1);
    __syncthreads();
    sc[t] = cnt[t];
    __syncthreads();
    for (int off = 1; off < 512; off <<= 1) {
        int add = (t >= off) ? sc[t - off] : 0;
        __syncthreads();
        sc[t] += add;
        __syncthreads();
    }
    const int nb0 = b * 512;
    if (nb0 + t < N) offsets[nb0 + t] = s + sc[t] - cnt[t];
    for (int i = s + t; i < e; i += 512) {
        uint32_t p = pbuf[i];
        int dl = (int)(p >> 17);
        int sr = (int)(p & 0x1FFFFu);
        int pos = s + (sc[dl] - cnt[dl]) + atomicAdd(&fil[dl], 1);
        srcs_sort[pos] = sr;
    }
}

// ---------------- FUSED aggregate + SAGE linear ----------------
// Block = 4 waves = 32 nodes (N % 32 == 0).
// Phase 1: stage self rows -> LDS; each wave mean-aggregates 8 nodes (pair
//          scheme: lanes 0-31 = edge A, lanes 32-63 = edge B) -> bf16 into LDS.
// Phase 2: 32x128 GEMM from LDS: D = mfma(W_frag, X_frag); lane holds 4
//          consecutive channels of one node -> contiguous stores.
// LDS rows padded to K+8 ushorts to break phase-2 bank conflicts.
template<int K, bool RELU, bool OUT_BF16>
__global__ __launch_bounds__(256) void sage_fused(
    const int* __restrict__ offsets, const int* __restrict__ srcs,
    const ushort* __restrict__ xin, const ushort* __restrict__ Wcat,
    const float* __restrict__ bl, void* __restrict__ outv, int N)
{
    constexpr int KT = 2 * K;
    constexpr int RP = K + 8;                 // padded row (ushorts)
    __shared__ ushort mlds[32][RP];
    __shared__ ushort slds[32][RP];
    const int t = threadIdx.x;
    const int w = t >> 6;
    const int lane = t & 63;
    const int nb = blockIdx.x * 32;

    // stage self rows (coalesced 16B chunks)
    #pragma unroll
    for (int idx = t; idx < 32 * (K / 8); idx += 256) {
        int r = idx / (K / 8), c = idx % (K / 8);
        *(uint4*)&slds[r][c * 8] = *(const uint4*)&xin[(size_t)(nb + r) * K + c * 8];
    }

    const int half = lane >> 5;
    const int sl = lane & 31;

    // phase 1: aggregate 8 nodes per wave
    for (int i = 0; i < 8; i++) {
        const int ln = w * 8 + i;
        const int node = nb + ln;
        int s0 = offsets[node], s1 = offsets[node + 1];
        float inv = 1.0f / fmaxf((float)(s1 - s0), 1.0f);

        if (K == 64) {
            float ax0=0.f, ay0=0.f, ax1=0.f, ay1=0.f, ax2=0.f, ay2=0.f, ax3=0.f, ay3=0.f;
            for (int base = s0; base < s1; base += 64) {
                int cnt = min(64, s1 - base);
                int myidx = (base + lane < s1) ? srcs[base + lane] : 0;
                int j = 0;
                for (; j + 8 <= cnt; j += 8) {
                    int sA = __shfl(myidx, j + half);
                    int sB = __shfl(myidx, j + 2 + half);
                    int sC = __shfl(myidx, j + 4 + half);
                    int sD = __shfl(myidx, j + 6 + half);
                    uint32_t uA = *(const uint32_t*)&xin[(size_t)sA * 64 + sl * 2];
                    uint32_t uB = *(const uint32_t*)&xin[(size_t)sB * 64 + sl * 2];
                    uint32_t uC = *(const uint32_t*)&xin[(size_t)sC * 64 + sl * 2];
                    uint32_t uD = *(const uint32_t*)&xin[(size_t)sD * 64 + sl * 2];
                    ax0 += bflo(uA); ay0 += bfhi(uA);
                    ax1 += bflo(uB); ay1 += bfhi(uB);
                    ax2 += bflo(uC); ay2 += bfhi(uC);
                    ax3 += bflo(uD); ay3 += bfhi(uD);
                }
                for (; j + 2 <= cnt; j += 2) {
                    int s = __shfl(myidx, j + half);
                    uint32_t u = *(const uint32_t*)&xin[(size_t)s * 64 + sl * 2];
                    ax0 += bflo(u); ay0 += bfhi(u);
                }
                int st = __shfl(myidx, j & 63);      // hoisted out of divergent branch
                if (j < cnt && half == 0) {
                    uint32_t u = *(const uint32_t*)&xin[(size_t)st * 64 + sl * 2];
                    ax0 += bflo(u); ay0 += bfhi(u);
                }
            }
            float ax = ax0 + ax1 + ax2 + ax3;
            float ay = ay0 + ay1 + ay2 + ay3;
            ax += __shfl_xor(ax, 32);
            ay += __shfl_xor(ay, 32);
            if (half == 0) {
                ushort o[2] = { f2bf(ax * inv), f2bf(ay * inv) };
                *(uint32_t*)&mlds[ln][sl * 2] = *(const uint32_t*)o;
            }
        } else {
            float a0=0.f, a1=0.f, a2=0.f, a3=0.f;
            float b0=0.f, b1=0.f, b2=0.f, b3=0.f;
            float c0=0.f, c1=0.f, c2=0.f, c3=0.f;
            float d0=0.f, d1=0.f, d2=0.f, d3=0.f;
            for (int base = s0; base < s1; base += 64) {
                int cnt = min(64, s1 - base);
                int myidx = (base + lane < s1) ? srcs[base + lane] : 0;
                int j = 0;
                for (; j + 8 <= cnt; j += 8) {
                    int sA = __shfl(myidx, j + half);
                    int sB = __shfl(myidx, j + 2 + half);
                    int sC = __shfl(myidx, j + 4 + half);
                    int sD = __shfl(myidx, j + 6 + half);
                    uint2 uA = *(const uint2*)&xin[(size_t)sA * 128 + sl * 4];
                    uint2 uB = *(const uint2*)&xin[(size_t)sB * 128 + sl * 4];
                    uint2 uC = *(const uint2*)&xin[(size_t)sC * 128 + sl * 4];
                    uint2 uD = *(const uint2*)&xin[(size_t)sD * 128 + sl * 4];
                    a0 += bflo(uA.x); a1 += bfhi(uA.x); a2 += bflo(uA.y); a3 += bfhi(uA.y);
                    b0 += bflo(uB.x); b1 += bfhi(uB.x); b2 += bflo(uB.y); b3 += bfhi(uB.y);
                    c0 += bflo(uC.x); c1 += bfhi(uC.x); c2 += bflo(uC.y); c3 += bfhi(uC.y);
                    d0 += bflo(uD.x); d1 += bfhi(uD.x); d2 += bflo(uD.y); d3 += bfhi(uD.y);
                }
                for (; j + 2 <= cnt; j += 2) {
                    int s = __shfl(myidx, j + half);
                    uint2 u = *(const uint2*)&xin[(size_t)s * 128 + sl * 4];
                    a0 += bflo(u.x); a1 += bfhi(u.x); a2 += bflo(u.y); a3 += bfhi(u.y);
                }
                int st = __shfl(myidx, j & 63);      // hoisted out of divergent branch
                if (j < cnt && half == 0) {
                    uint2 u = *(const uint2*)&xin[(size_t)st * 128 + sl * 4];
                    a0 += bflo(u.x); a1 += bfhi(u.x); a2 += bflo(u.y); a3 += bfhi(u.y);
                }
            }
            float v0 = a0 + b0 + c0 + d0;
            float v1 = a1 + b1 + c1 + d1;
            float v2 = a2 + b2 + c2 + d2;
            float v3 = a3 + b3 + c3 + d3;
            v0 += __shfl_xor(v0, 32);
            v1 += __shfl_xor(v1, 32);
            v2 += __shfl_xor(v2, 32);
            v3 += __shfl_xor(v3, 32);
            if (half == 0) {
                ushort o[4] = { f2bf(v0 * inv), f2bf(v1 * inv), f2bf(v2 * inv), f2bf(v3 * inv) };
                *(uint64_t*)&mlds[ln][sl * 4] = *(const uint64_t*)o;
            }
        }
    }
    __syncthreads();

    // phase 2: GEMM 32 nodes x 128 channels; wave w owns channels w*32..w*32+31
    const int lrow = lane & 15;
    const int lgrp = lane >> 4;
    f32x4 acc[2][2];                       // [node-tile][ch-tile]
    #pragma unroll
    for (int nt = 0; nt < 2; nt++)
        #pragma unroll
        for (int ct = 0; ct < 2; ct++)
            acc[nt][ct] = (f32x4){0.f, 0.f, 0.f, 0.f};

    #pragma unroll
    for (int ks = 0; ks < KT; ks += 32) {
        const int ac = (ks < K) ? ks : (ks - K);
        const ushort* Xb = (ks < K) ? &mlds[0][0] : &slds[0][0];
        bf16x8 x0 = *(const bf16x8*)&Xb[(lrow) * RP + ac + lgrp * 8];
        bf16x8 x1 = *(const bf16x8*)&Xb[(16 + lrow) * RP + ac + lgrp * 8];
        bf16x8 wA = *(const bf16x8*)&Wcat[(size_t)(w * 32 + lrow) * KT + ks + lgrp * 8];
        bf16x8 wB = *(const bf16x8*)&Wcat[(size_t)(w * 32 + 16 + lrow) * KT + ks + lgrp * 8];
        acc[0][0] = __builtin_amdgcn_mfma_f32_16x16x32_bf16(wA, x0, acc[0][0], 0, 0, 0);
        acc[0][1] = __builtin_amdgcn_mfma_f32_16x16x32_bf16(wB, x0, acc[0][1], 0, 0, 0);
        acc[1][0] = __builtin_amdgcn_mfma_f32_16x16x32_bf16(wA, x1, acc[1][0], 0, 0, 0);
        acc[1][1] = __builtin_amdgcn_mfma_f32_16x16x32_bf16(wB, x1, acc[1][1], 0, 0, 0);
    }

    // epilogue: lane holds channels (w*32 + ct*16 + lgrp*4 .. +3) of node nb+nt*16+lrow
    #pragma unroll
    for (int ct = 0; ct < 2; ct++) {
        const int ch0 = w * 32 + ct * 16 + lgrp * 4;
        float4 b4 = *(const float4*)&bl[ch0];
        #pragma unroll
        for (int nt = 0; nt < 2; nt++) {
            int n = nb + nt * 16 + lrow;
            float v0 = acc[nt][ct][0] + b4.x;
            float v1 = acc[nt][ct][1] + b4.y;
            float v2 = acc[nt][ct][2] + b4.z;
            float v3 = acc[nt][ct][3] + b4.w;
            if (RELU) {
                v0 = fmaxf(v0, 0.f); v1 = fmaxf(v1, 0.f);
                v2 = fmaxf(v2, 0.f); v3 = fmaxf(v3, 0.f);
            }
            if (OUT_BF16) {
                ushort o[4] = { f2bf(v0), f2bf(v1), f2bf(v2), f2bf(v3) };
                *(uint64_t*)&((ushort*)outv)[(size_t)n * 128 + ch0] = *(const uint64_t*)o;
            } else {
                float4 o = make_float4(v0, v1, v2, v3);
                *(float4*)&((float*)outv)[(size_t)n * 128 + ch0] = o;
            }
        }
    }
}

// ---------------- launch ----------------
extern "C" void kernel_launch(void* const* d_in, const int* in_sizes, int n_in,
                              void* d_out, int out_size, void* d_ws, size_t ws_size,
                              hipStream_t stream) {
    const float* x   = (const float*)d_in[0];
    const void*  er  = d_in[1];
    const float* Wl1 = (const float*)d_in[2];
    const float* bl1 = (const float*)d_in[3];
    const float* Wr1 = (const float*)d_in[4];
    const float* Wl2 = (const float*)d_in[5];
    const float* bl2 = (const float*)d_in[6];
    const float* Wr2 = (const float*)d_in[7];
    float* out = (float*)d_out;

    const int N = NN, E = EE;

    // workspace carve-up (512B aligned)
    char* ws = (char*)d_ws;
    size_t off = 0;
    auto carve = [&](size_t bytes) { char* p = ws + off; off += (bytes + 511) & ~(size_t)511; return p; };
    int*      flag      = (int*)     carve(4);
    int*      ccnt      = (int*)     carve((size_t)NBUCK * 4);
    int*      cfill     = (int*)     carve((size_t)NBUCK * 4);
    int*      coff      = (int*)     carve((size_t)(NBUCK + 1) * 4);
    uint32_t* pbuf      = (uint32_t*)carve((size_t)E * 4);
    int*      offsets   = (int*)     carve((size_t)(N + 1) * 4);
    int*      srcs_sort = (int*)     carve((size_t)E * 4);
    ushort*   xb        = (ushort*)  carve((size_t)N * 64 * 2);
    ushort*   hb        = (ushort*)  carve((size_t)N * 128 * 2);
    ushort*   wc1       = (ushort*)  carve((size_t)128 * 128 * 2);
    ushort*   wc2       = (ushort*)  carve((size_t)128 * 256 * 2);
    (void)ws_size;

    hipMemsetAsync(flag, 0, 4, stream);
    hipMemsetAsync(ccnt, 0, (size_t)NBUCK * 4, stream);
    hipMemsetAsync(cfill, 0, (size_t)NBUCK * 4, stream);

    detect_kernel<<<16, 256, 0, stream>>>((const unsigned int*)er, flag);

    // bf16 conversions (independent of CSR build)
    cvt_f32_bf16<<<(N * 64 / 4 + 255) / 256, 256, 0, stream>>>(x, xb, N * 64 / 4);
    build_wcat<<<(128 * 128 + 255) / 256, 256, 0, stream>>>(Wl1, Wr1, wc1, 64);
    build_wcat<<<(128 * 256 + 255) / 256, 256, 0, stream>>>(Wl2, Wr2, wc2, 128);

    // CSR build: two-level partition with block-level reservation
    coarse_hist<<<512, 256, 0, stream>>>(er, flag, ccnt, E);
    coarse_scan<<<1, 256, 0, stream>>>(ccnt, coff, offsets, E);
    coarse_scatter2<<<CSB, 256, 0, stream>>>(er, flag, coff, cfill, pbuf, E);
    fine_bucket<<<NBUCK, 512, 0, stream>>>(pbuf, coff, offsets, srcs_sort, N);

    const int fb = N / 32;                                   // 3125 (N % 32 == 0)

    // layer 1 (fused aggregate + linear, relu, bf16 out)
    sage_fused<64, true, true><<<fb, 256, 0, stream>>>(offsets, srcs_sort, xb, wc1, bl1, hb, N);
    // layer 2 (fused aggregate + linear, f32 out)
    sage_fused<128, false, false><<<fb, 256, 0, stream>>>(offsets, srcs_sort, hb, wc2, bl2, out, N);
}

// Round 10
// 210.434 us; speedup vs baseline: 3.0417x; 1.0391x over previous
//
#include <hip/hip_runtime.h>
#include <hip/hip_bf16.h>
#include <stdint.h>

#define NN 100000
#define EE 1600000
#define NBUCK 196              // ceil(NN/512): buckets of 512 dst nodes
#define CSB 512                // coarse-scatter blocks

typedef __attribute__((ext_vector_type(4))) float f32x4;
typedef __attribute__((ext_vector_type(8))) short bf16x8;

__device__ inline ushort f2bf(float f) {
    union { float f; uint32_t u; } v; v.f = f;
    uint32_t u = v.u;
    uint32_t r = (u + 0x7fffu + ((u >> 16) & 1u)) >> 16;   // RNE
    return (ushort)r;
}
__device__ inline float bflo(uint32_t u) {
    union { uint32_t u; float f; } v; v.u = u << 16; return v.f;
}
__device__ inline float bfhi(uint32_t u) {
    union { uint32_t u; float f; } v; v.u = u & 0xffff0000u; return v.f;
}

// ---------------- edge dtype detect ----------------
__global__ void detect_kernel(const unsigned int* raw, int* flag) {
    int i = blockIdx.x * blockDim.x + threadIdx.x;
    if (i < 4096) {
        if (raw[2 * i + 1] != 0u) atomicOr(flag, 1);
    }
}

// ---------------- dtype conversion passes ----------------
__global__ void cvt_f32_bf16(const float* __restrict__ in, ushort* __restrict__ out, int n4) {
    int i = blockIdx.x * blockDim.x + threadIdx.x;   // one float4 per thread
    if (i >= n4) return;
    float4 v = *(const float4*)&in[i * 4];
    ushort o[4] = { f2bf(v.x), f2bf(v.y), f2bf(v.z), f2bf(v.w) };
    *(uint64_t*)&out[i * 4] = *(const uint64_t*)o;
}

// Wcat[o][0..K) = Wl[o][:], Wcat[o][K..2K) = Wr[o][:]  (bf16)
__global__ void build_wcat(const float* __restrict__ Wl, const float* __restrict__ Wr,
                           ushort* __restrict__ Wcat, int K) {
    int t = blockIdx.x * blockDim.x + threadIdx.x;
    int KT = 2 * K;
    if (t >= 128 * KT) return;
    int o = t / KT, k = t % KT;
    float v = (k < K) ? Wl[o * K + k] : Wr[o * K + (k - K)];
    Wcat[o * KT + k] = f2bf(v);
}

// ---------------- CSR build: two-level partition (block-reserved) ----------------
__global__ __launch_bounds__(256) void coarse_hist(const void* raw, const int* flag,
                                                   int* ccnt, int E) {
    __shared__ int lh[NBUCK];
    for (int i = threadIdx.x; i < NBUCK; i += 256) lh[i] = 0;
    __syncthreads();
    int stride = gridDim.x * 256;
    if (*flag) {
        const int* p = (const int*)raw;
        for (int e = blockIdx.x * 256 + threadIdx.x; e < E; e += stride)
            atomicAdd(&lh[p[E + e] >> 9], 1);
    } else {
        const long long* p = (const long long*)raw;
        for (int e = blockIdx.x * 256 + threadIdx.x; e < E; e += stride)
            atomicAdd(&lh[((int)p[E + e]) >> 9], 1);
    }
    __syncthreads();
    for (int i = threadIdx.x; i < NBUCK; i += 256)
        if (lh[i]) atomicAdd(&ccnt[i], lh[i]);
}

__global__ void coarse_scan(const int* ccnt, int* coff, int* offsets, int E) {
    __shared__ int part[256];
    int t = threadIdx.x;
    int v[4]; int s = 0;
    #pragma unroll
    for (int j = 0; j < 4; j++) {
        int i = t * 4 + j;
        v[j] = (i < NBUCK) ? ccnt[i] : 0;
        s += v[j];
    }
    part[t] = s; __syncthreads();
    for (int off = 1; off < 256; off <<= 1) {
        int add = (t >= off) ? part[t - off] : 0;
        __syncthreads();
        part[t] += add;
        __syncthreads();
    }
    int run = part[t] - s;
    #pragma unroll
    for (int j = 0; j < 4; j++) {
        int i = t * 4 + j;
        if (i <= NBUCK) coff[i] = run;
        run += v[j];
    }
    if (t == 0) offsets[NN] = E;
}

__global__ __launch_bounds__(256) void coarse_scatter2(const void* raw, const int* flag,
                                                       const int* coff, int* cfill,
                                                       uint32_t* pbuf, int E) {
    __shared__ int lh[NBUCK];
    __shared__ int gbase[NBUCK];
    __shared__ int lfill[NBUCK];
    const int t = threadIdx.x;
    for (int i = t; i < NBUCK; i += 256) { lh[i] = 0; lfill[i] = 0; }
    __syncthreads();
    const int chunk = (E + (int)gridDim.x - 1) / (int)gridDim.x;
    const int s0 = blockIdx.x * chunk;
    const int s1 = min(E, s0 + chunk);
    const bool is32 = (*flag != 0);
    if (is32) {
        const int* p = (const int*)raw;
        for (int e = s0 + t; e < s1; e += 256) atomicAdd(&lh[p[E + e] >> 9], 1);
    } else {
        const long long* p = (const long long*)raw;
        for (int e = s0 + t; e < s1; e += 256) atomicAdd(&lh[((int)p[E + e]) >> 9], 1);
    }
    __syncthreads();
    for (int i = t; i < NBUCK; i += 256)
        gbase[i] = coff[i] + (lh[i] ? atomicAdd(&cfill[i], lh[i]) : 0);
    __syncthreads();
    if (is32) {
        const int* p = (const int*)raw;
        for (int e = s0 + t; e < s1; e += 256) {
            int sr = p[e], d = p[E + e];
            int b = d >> 9;
            int r = atomicAdd(&lfill[b], 1);
            pbuf[gbase[b] + r] = ((uint32_t)(d & 511) << 17) | (uint32_t)sr;
        }
    } else {
        const long long* p = (const long long*)raw;
        for (int e = s0 + t; e < s1; e += 256) {
            int sr = (int)p[e], d = (int)p[E + e];
            int b = d >> 9;
            int r = atomicAdd(&lfill[b], 1);
            pbuf[gbase[b] + r] = ((uint32_t)(d & 511) << 17) | (uint32_t)sr;
        }
    }
}

__global__ __launch_bounds__(512) void fine_bucket(const uint32_t* __restrict__ pbuf,
                                                   const int* __restrict__ coff,
                                                   int* __restrict__ offsets,
                                                   int* __restrict__ srcs_sort, int N) {
    __shared__ int cnt[512], sc[512], fil[512];
    const int b = blockIdx.x, t = threadIdx.x;
    const int s = coff[b], e = coff[b + 1];
    cnt[t] = 0; fil[t] = 0;
    __syncthreads();
    for (int i = s + t; i < e; i += 512) atomicAdd(&cnt[pbuf[i] >> 17], 1);
    __syncthreads();
    sc[t] = cnt[t];
    __syncthreads();
    for (int off = 1; off < 512; off <<= 1) {
        int add = (t >= off) ? sc[t - off] : 0;
        __syncthreads();
        sc[t] += add;
        __syncthreads();
    }
    const int nb0 = b * 512;
    if (nb0 + t < N) offsets[nb0 + t] = s + sc[t] - cnt[t];
    for (int i = s + t; i < e; i += 512) {
        uint32_t p = pbuf[i];
        int dl = (int)(p >> 17);
        int sr = (int)(p & 0x1FFFFu);
        int pos = s + (sc[dl] - cnt[dl]) + atomicAdd(&fil[dl], 1);
        srcs_sort[pos] = sr;
    }
}

// ---------------- FUSED aggregate + SAGE linear ----------------
// Block = 4 waves = 32 nodes (N % 32 == 0).
// Phase 1 (node-per-half-wave): lanes 0-31 aggregate node A, lanes 32-63
//   node B — two independent edge streams per wave (8 gathers in flight),
//   no cross-half reduce, no divergent-tail shuffles. Per-wave offsets
//   batched via one lane<9 load + shfl broadcast.
// Phase 2: 32x128 GEMM from LDS (swapped-operand MFMA, contiguous stores).
// LDS rows padded to K+8 ushorts to break phase-2 bank conflicts.
template<int K, bool RELU, bool OUT_BF16>
__global__ __launch_bounds__(256) void sage_fused(
    const int* __restrict__ offsets, const int* __restrict__ srcs,
    const ushort* __restrict__ xin, const ushort* __restrict__ Wcat,
    const float* __restrict__ bl, void* __restrict__ outv, int N)
{
    constexpr int KT = 2 * K;
    constexpr int RP = K + 8;                 // padded row (ushorts)
    __shared__ ushort mlds[32][RP];
    __shared__ ushort slds[32][RP];
    const int t = threadIdx.x;
    const int w = t >> 6;
    const int lane = t & 63;
    const int nb = blockIdx.x * 32;

    // stage self rows (coalesced 16B chunks)
    #pragma unroll
    for (int idx = t; idx < 32 * (K / 8); idx += 256) {
        int r = idx / (K / 8), c = idx % (K / 8);
        *(uint4*)&slds[r][c * 8] = *(const uint4*)&xin[(size_t)(nb + r) * K + c * 8];
    }

    const int half = lane >> 5;
    const int sl = lane & 31;
    const int hbase = lane & 32;              // shfl base of own half

    // batch-load the 9 offsets this wave needs
    int offv = 0;
    if (lane < 9) offv = offsets[nb + w * 8 + lane];

    // phase 1: 4 node-pairs per wave; each half-wave owns one node
    for (int pi = 0; pi < 4; pi++) {
        const int ln = w * 8 + pi * 2 + half;         // local node index
        const int s0 = __shfl(offv, pi * 2 + half);
        const int s1 = __shfl(offv, pi * 2 + half + 1);
        const float inv = 1.0f / fmaxf((float)(s1 - s0), 1.0f);

        if (K == 64) {
            // lane covers channels 2sl..2sl+1 (uint32 = 2 bf16)
            float x0=0.f, y0=0.f, x1=0.f, y1=0.f, x2=0.f, y2=0.f, x3=0.f, y3=0.f;
            for (int base = s0; base < s1; base += 32) {
                int cnt = min(32, s1 - base);
                int myidx = (base + sl < s1) ? srcs[base + sl] : 0;
                int j = 0;
                for (; j + 4 <= cnt; j += 4) {
                    int sA = __shfl(myidx, hbase + j);
                    int sB = __shfl(myidx, hbase + j + 1);
                    int sC = __shfl(myidx, hbase + j + 2);
                    int sD = __shfl(myidx, hbase + j + 3);
                    uint32_t uA = *(const uint32_t*)&xin[(size_t)sA * 64 + sl * 2];
                    uint32_t uB = *(const uint32_t*)&xin[(size_t)sB * 64 + sl * 2];
                    uint32_t uC = *(const uint32_t*)&xin[(size_t)sC * 64 + sl * 2];
                    uint32_t uD = *(const uint32_t*)&xin[(size_t)sD * 64 + sl * 2];
                    x0 += bflo(uA); y0 += bfhi(uA);
                    x1 += bflo(uB); y1 += bfhi(uB);
                    x2 += bflo(uC); y2 += bfhi(uC);
                    x3 += bflo(uD); y3 += bfhi(uD);
                }
                for (; j < cnt; j++) {
                    int s = __shfl(myidx, hbase + j);
                    uint32_t u = *(const uint32_t*)&xin[(size_t)s * 64 + sl * 2];
                    x0 += bflo(u); y0 += bfhi(u);
                }
            }
            float ax = x0 + x1 + x2 + x3;
            float ay = y0 + y1 + y2 + y3;
            ushort o[2] = { f2bf(ax * inv), f2bf(ay * inv) };
            *(uint32_t*)&mlds[ln][sl * 2] = *(const uint32_t*)o;
        } else {
            // lane covers channels 4sl..4sl+3 (uint2 = 4 bf16)
            float a0=0.f, a1=0.f, a2=0.f, a3=0.f;
            float b0=0.f, b1=0.f, b2=0.f, b3=0.f;
            float c0=0.f, c1=0.f, c2=0.f, c3=0.f;
            float d0=0.f, d1=0.f, d2=0.f, d3=0.f;
            for (int base = s0; base < s1; base += 32) {
                int cnt = min(32, s1 - base);
                int myidx = (base + sl < s1) ? srcs[base + sl] : 0;
                int j = 0;
                for (; j + 4 <= cnt; j += 4) {
                    int sA = __shfl(myidx, hbase + j);
                    int sB = __shfl(myidx, hbase + j + 1);
                    int sC = __shfl(myidx, hbase + j + 2);
                    int sD = __shfl(myidx, hbase + j + 3);
                    uint2 uA = *(const uint2*)&xin[(size_t)sA * 128 + sl * 4];
                    uint2 uB = *(const uint2*)&xin[(size_t)sB * 128 + sl * 4];
                    uint2 uC = *(const uint2*)&xin[(size_t)sC * 128 + sl * 4];
                    uint2 uD = *(const uint2*)&xin[(size_t)sD * 128 + sl * 4];
                    a0 += bflo(uA.x); a1 += bfhi(uA.x); a2 += bflo(uA.y); a3 += bfhi(uA.y);
                    b0 += bflo(uB.x); b1 += bfhi(uB.x); b2 += bflo(uB.y); b3 += bfhi(uB.y);
                    c0 += bflo(uC.x); c1 += bfhi(uC.x); c2 += bflo(uC.y); c3 += bfhi(uC.y);
                    d0 += bflo(uD.x); d1 += bfhi(uD.x); d2 += bflo(uD.y); d3 += bfhi(uD.y);
                }
                for (; j < cnt; j++) {
                    int s = __shfl(myidx, hbase + j);
                    uint2 u = *(const uint2*)&xin[(size_t)s * 128 + sl * 4];
                    a0 += bflo(u.x); a1 += bfhi(u.x); a2 += bflo(u.y); a3 += bfhi(u.y);
                }
            }
            float v0 = a0 + b0 + c0 + d0;
            float v1 = a1 + b1 + c1 + d1;
            float v2 = a2 + b2 + c2 + d2;
            float v3 = a3 + b3 + c3 + d3;
            ushort o[4] = { f2bf(v0 * inv), f2bf(v1 * inv), f2bf(v2 * inv), f2bf(v3 * inv) };
            *(uint64_t*)&mlds[ln][sl * 4] = *(const uint64_t*)o;
        }
    }
    __syncthreads();

    // phase 2: GEMM 32 nodes x 128 channels; wave w owns channels w*32..w*32+31
    const int lrow = lane & 15;
    const int lgrp = lane >> 4;
    f32x4 acc[2][2];                       // [node-tile][ch-tile]
    #pragma unroll
    for (int nt = 0; nt < 2; nt++)
        #pragma unroll
        for (int ct = 0; ct < 2; ct++)
            acc[nt][ct] = (f32x4){0.f, 0.f, 0.f, 0.f};

    #pragma unroll
    for (int ks = 0; ks < KT; ks += 32) {
        const int ac = (ks < K) ? ks : (ks - K);
        const ushort* Xb = (ks < K) ? &mlds[0][0] : &slds[0][0];
        bf16x8 x0 = *(const bf16x8*)&Xb[(lrow) * RP + ac + lgrp * 8];
        bf16x8 x1 = *(const bf16x8*)&Xb[(16 + lrow) * RP + ac + lgrp * 8];
        bf16x8 wA = *(const bf16x8*)&Wcat[(size_t)(w * 32 + lrow) * KT + ks + lgrp * 8];
        bf16x8 wB = *(const bf16x8*)&Wcat[(size_t)(w * 32 + 16 + lrow) * KT + ks + lgrp * 8];
        acc[0][0] = __builtin_amdgcn_mfma_f32_16x16x32_bf16(wA, x0, acc[0][0], 0, 0, 0);
        acc[0][1] = __builtin_amdgcn_mfma_f32_16x16x32_bf16(wB, x0, acc[0][1], 0, 0, 0);
        acc[1][0] = __builtin_amdgcn_mfma_f32_16x16x32_bf16(wA, x1, acc[1][0], 0, 0, 0);
        acc[1][1] = __builtin_amdgcn_mfma_f32_16x16x32_bf16(wB, x1, acc[1][1], 0, 0, 0);
    }

    // epilogue: lane holds channels (w*32 + ct*16 + lgrp*4 .. +3) of node nb+nt*16+lrow
    #pragma unroll
    for (int ct = 0; ct < 2; ct++) {
        const int ch0 = w * 32 + ct * 16 + lgrp * 4;
        float4 b4 = *(const float4*)&bl[ch0];
        #pragma unroll
        for (int nt = 0; nt < 2; nt++) {
            int n = nb + nt * 16 + lrow;
            float v0 = acc[nt][ct][0] + b4.x;
            float v1 = acc[nt][ct][1] + b4.y;
            float v2 = acc[nt][ct][2] + b4.z;
            float v3 = acc[nt][ct][3] + b4.w;
            if (RELU) {
                v0 = fmaxf(v0, 0.f); v1 = fmaxf(v1, 0.f);
                v2 = fmaxf(v2, 0.f); v3 = fmaxf(v3, 0.f);
            }
            if (OUT_BF16) {
                ushort o[4] = { f2bf(v0), f2bf(v1), f2bf(v2), f2bf(v3) };
                *(uint64_t*)&((ushort*)outv)[(size_t)n * 128 + ch0] = *(const uint64_t*)o;
            } else {
                float4 o = make_float4(v0, v1, v2, v3);
                *(float4*)&((float*)outv)[(size_t)n * 128 + ch0] = o;
            }
        }
    }
}

// ---------------- launch ----------------
extern "C" void kernel_launch(void* const* d_in, const int* in_sizes, int n_in,
                              void* d_out, int out_size, void* d_ws, size_t ws_size,
                              hipStream_t stream) {
    const float* x   = (const float*)d_in[0];
    const void*  er  = d_in[1];
    const float* Wl1 = (const float*)d_in[2];
    const float* bl1 = (const float*)d_in[3];
    const float* Wr1 = (const float*)d_in[4];
    const float* Wl2 = (const float*)d_in[5];
    const float* bl2 = (const float*)d_in[6];
    const float* Wr2 = (const float*)d_in[7];
    float* out = (float*)d_out;

    const int N = NN, E = EE;

    // workspace carve-up (512B aligned)
    char* ws = (char*)d_ws;
    size_t off = 0;
    auto carve = [&](size_t bytes) { char* p = ws + off; off += (bytes + 511) & ~(size_t)511; return p; };
    int*      flag      = (int*)     carve(4);
    int*      ccnt      = (int*)     carve((size_t)NBUCK * 4);
    int*      cfill     = (int*)     carve((size_t)NBUCK * 4);
    int*      coff      = (int*)     carve((size_t)(NBUCK + 1) * 4);
    uint32_t* pbuf      = (uint32_t*)carve((size_t)E * 4);
    int*      offsets   = (int*)     carve((size_t)(N + 1) * 4);
    int*      srcs_sort = (int*)     carve((size_t)E * 4);
    ushort*   xb        = (ushort*)  carve((size_t)N * 64 * 2);
    ushort*   hb        = (ushort*)  carve((size_t)N * 128 * 2);
    ushort*   wc1       = (ushort*)  carve((size_t)128 * 128 * 2);
    ushort*   wc2       = (ushort*)  carve((size_t)128 * 256 * 2);
    (void)ws_size;

    hipMemsetAsync(flag, 0, 4, stream);
    hipMemsetAsync(ccnt, 0, (size_t)NBUCK * 4, stream);
    hipMemsetAsync(cfill, 0, (size_t)NBUCK * 4, stream);

    detect_kernel<<<16, 256, 0, stream>>>((const unsigned int*)er, flag);

    // bf16 conversions (independent of CSR build)
    cvt_f32_bf16<<<(N * 64 / 4 + 255) / 256, 256, 0, stream>>>(x, xb, N * 64 / 4);
    build_wcat<<<(128 * 128 + 255) / 256, 256, 0, stream>>>(Wl1, Wr1, wc1, 64);
    build_wcat<<<(128 * 256 + 255) / 256, 256, 0, stream>>>(Wl2, Wr2, wc2, 128);

    // CSR build: two-level partition with block-level reservation
    coarse_hist<<<512, 256, 0, stream>>>(er, flag, ccnt, E);
    coarse_scan<<<1, 256, 0, stream>>>(ccnt, coff, offsets, E);
    coarse_scatter2<<<CSB, 256, 0, stream>>>(er, flag, coff, cfill, pbuf, E);
    fine_bucket<<<NBUCK, 512, 0, stream>>>(pbuf, coff, offsets, srcs_sort, N);

    const int fb = N / 32;                                   // 3125 (N % 32 == 0)

    // layer 1 (fused aggregate + linear, relu, bf16 out)
    sage_fused<64, true, true><<<fb, 256, 0, stream>>>(offsets, srcs_sort, xb, wc1, bl1, hb, N);
    // layer 2 (fused aggregate + linear, f32 out)
    sage_fused<128, false, false><<<fb, 256, 0, stream>>>(offsets, srcs_sort, hb, wc2, bl2, out, N);
}